// Round 1
// 1952.101 us; speedup vs baseline: 1.0707x; 1.0707x over previous
//
#include <hip/hip_runtime.h>
#include <cstddef>
#include <cstdint>

// Problem constants (fixed by setup_inputs)
#define T_   8
#define N_   10000
#define E_   320000
#define F_   128
#define D1_  128
#define D2_  64
#define DR_  128
#define NC_  100
#define TN_  (T_*N_)
#define TE_  (T_*E_)
#define NPAD_ 10112   // 79*128, row padding for M=10000 MFMA tiles

typedef __attribute__((ext_vector_type(8))) short bf16x8;
typedef __attribute__((ext_vector_type(8))) ushort u16x8;
typedef __attribute__((ext_vector_type(4))) float f32x4;

__device__ __forceinline__ float bf2f(ushort u) {
    return __uint_as_float(((unsigned int)u) << 16);
}
__device__ __forceinline__ ushort f2bf(float f) {
    unsigned int u = __float_as_uint(f);
    unsigned int r = (u + 0x7FFFu + ((u >> 16) & 1u)) >> 16;   // RNE
    return (ushort)r;
}
// numerically safe fast tanh / sigmoid (inf-safe forms)
__device__ __forceinline__ float fast_tanh(float x) {
    float t = __expf(2.f * x);
    return 1.f - 2.f / (t + 1.f);
}
__device__ __forceinline__ float fast_sigmoid(float x) {
    return 1.f / (1.f + __expf(-x));
}

// ---------------------------------------------------------------------------
// fp32 -> bf16 bulk convert (feat). 8 elems/thread.
// ---------------------------------------------------------------------------
__global__ __launch_bounds__(256) void conv_feat(const float* __restrict__ src,
                                                 ushort* __restrict__ dst, int n8)
{
    int idx = blockIdx.x * 256 + threadIdx.x;
    if (idx >= n8) return;
    const float4* s = (const float4*)src + (size_t)idx * 2;
    float4 x = s[0], y = s[1];
    u16x8 o;
    o[0]=f2bf(x.x); o[1]=f2bf(x.y); o[2]=f2bf(x.z); o[3]=f2bf(x.w);
    o[4]=f2bf(y.x); o[5]=f2bf(y.y); o[6]=f2bf(y.z); o[7]=f2bf(y.w);
    *((u16x8*)dst + idx) = o;
}

// ---------------------------------------------------------------------------
// All weights -> transposed bf16 (BT[n][k] = W[k][n]) in one launch.
// Segments: W1 128x128, W2 128x64, Wx 128x512, Wh 128x512, eW 128x64, sW 128x64
// ---------------------------------------------------------------------------
__global__ __launch_bounds__(256) void conv_weights(
    const float* __restrict__ W1, const float* __restrict__ W2,
    const float* __restrict__ Wx, const float* __restrict__ Wh,
    const float* __restrict__ eW, const float* __restrict__ sW,
    ushort* __restrict__ W1T, ushort* __restrict__ W2T,
    ushort* __restrict__ WxT, ushort* __restrict__ WhT,
    ushort* __restrict__ eWT, ushort* __restrict__ sWT)
{
    int idx = blockIdx.x * 256 + threadIdx.x;
    if (idx < 16384)       { int n=idx>>7,   k=idx&127;            W1T[idx]=f2bf(W1[k*128+n]); }
    else if (idx < 24576)  { int l=idx-16384;  int n=l>>7,k=l&127; W2T[l]=f2bf(W2[k*64+n]); }
    else if (idx < 90112)  { int l=idx-24576;  int n=l>>7,k=l&127; WxT[l]=f2bf(Wx[k*512+n]); }
    else if (idx < 155648) { int l=idx-90112;  int n=l>>7,k=l&127; WhT[l]=f2bf(Wh[k*512+n]); }
    else if (idx < 163840) { int l=idx-155648; int n=l>>7,k=l&127; eWT[l]=f2bf(eW[k*64+n]); }
    else if (idx < 172032) { int l=idx-163840; int n=l>>7,k=l&127; sWT[l]=f2bf(sW[k*64+n]); }
}

// ---------------------------------------------------------------------------
// bf16 MFMA GEMM: C[M x Nc] = A[M x K] @ BT[Nc x K]^T  (+bias) (+addsrc) (act)
// K % 32 == 0, Nc % 64 == 0. Block 256 thr = 4 waves; tile 128 x 64; each wave
// computes 32 x 64 (2x4 tiles of 16x16, mfma_f32_16x16x32_bf16).
// A rows beyond M must be readable (caller pads allocations).
// act: 0 none, 1 tanh, 2 sigmoid.  Output to Cf (fp32) and/or Cb (bf16).
// ---------------------------------------------------------------------------
__global__ __launch_bounds__(256) void gemm_bf16(
    const ushort* __restrict__ A, const ushort* __restrict__ BT,
    float* __restrict__ Cf, ushort* __restrict__ Cb,
    const float* __restrict__ bias, const float* __restrict__ addsrc,
    int M, int K, int Nc, int act)
{
    int w = threadIdx.x >> 6, lane = threadIdx.x & 63;
    int quad = lane >> 4, l16 = lane & 15;
    int m0 = blockIdx.y * 128 + w * 32;
    int n0 = blockIdx.x * 64;
    f32x4 zf = {0.f, 0.f, 0.f, 0.f};
    f32x4 acc[2][4];
    #pragma unroll
    for (int rt = 0; rt < 2; ++rt)
        #pragma unroll
        for (int ct = 0; ct < 4; ++ct) acc[rt][ct] = zf;

    for (int k0 = 0; k0 < K; k0 += 32) {
        int kk = k0 + quad * 8;
        bf16x8 a0 = *(const bf16x8*)(A + (size_t)(m0 + l16) * K + kk);
        bf16x8 a1 = *(const bf16x8*)(A + (size_t)(m0 + 16 + l16) * K + kk);
        bf16x8 b[4];
        #pragma unroll
        for (int ct = 0; ct < 4; ++ct)
            b[ct] = *(const bf16x8*)(BT + (size_t)(n0 + ct * 16 + l16) * K + kk);
        #pragma unroll
        for (int ct = 0; ct < 4; ++ct) {
            acc[0][ct] = __builtin_amdgcn_mfma_f32_16x16x32_bf16(a0, b[ct], acc[0][ct], 0, 0, 0);
            acc[1][ct] = __builtin_amdgcn_mfma_f32_16x16x32_bf16(a1, b[ct], acc[1][ct], 0, 0, 0);
        }
    }

    #pragma unroll
    for (int rt = 0; rt < 2; ++rt) {
        int ibase = m0 + rt * 16 + quad * 4;
        #pragma unroll
        for (int r = 0; r < 4; ++r) {
            int i = ibase + r;
            if (i >= M) continue;
            #pragma unroll
            for (int ct = 0; ct < 4; ++ct) {
                int j = n0 + ct * 16 + l16;
                float v = acc[rt][ct][r];
                if (bias)   v += bias[j];
                if (addsrc) v += addsrc[(size_t)i * Nc + j];
                if (act == 1)      v = fast_tanh(v);
                else if (act == 2) v = fast_sigmoid(v);
                if (Cf) Cf[(size_t)i * Nc + j] = v;
                if (Cb) Cb[(size_t)i * Nc + j] = f2bf(v);
            }
        }
    }
}

// ---------------------------------------------------------------------------
// Per-node attention dots (bf16 h). One wave per row.
// ---------------------------------------------------------------------------
__global__ __launch_bounds__(256) void att_vec128(
    const ushort* __restrict__ h, const float* __restrict__ a_src,
    const float* __restrict__ a_dst, float* __restrict__ as_out,
    float* __restrict__ ad_out, int rows)
{
    int wid  = (blockIdx.x * 256 + threadIdx.x) >> 6;
    int lane = threadIdx.x & 63;
    if (wid >= rows) return;
    const ushort* hr = h + (size_t)wid * 128;
    float v0 = bf2f(hr[lane]), v1 = bf2f(hr[64 + lane]);
    float pa0 = v0 * a_src[lane], pa1 = v1 * a_src[64 + lane];
    float pd0 = v0 * a_dst[lane], pd1 = v1 * a_dst[64 + lane];
    #pragma unroll
    for (int m = 1; m <= 16; m <<= 1) {
        pa0 += __shfl_xor(pa0, m); pa1 += __shfl_xor(pa1, m);
        pd0 += __shfl_xor(pd0, m); pd1 += __shfl_xor(pd1, m);
    }
    if ((lane & 31) == 0) {
        int g = lane >> 5;
        as_out[wid * 4 + g] = pa0; as_out[wid * 4 + 2 + g] = pa1;
        ad_out[wid * 4 + g] = pd0; ad_out[wid * 4 + 2 + g] = pd1;
    }
}

__global__ __launch_bounds__(256) void att_vec64(
    const ushort* __restrict__ h, const float* __restrict__ a_src,
    const float* __restrict__ a_dst, float* __restrict__ as_out,
    float* __restrict__ ad_out, int rows)
{
    int wid  = (blockIdx.x * 256 + threadIdx.x) >> 6;
    int lane = threadIdx.x & 63;
    if (wid >= rows) return;
    float v = bf2f(h[(size_t)wid * 64 + lane]);
    float pa = v * a_src[lane], pd = v * a_dst[lane];
    #pragma unroll
    for (int m = 1; m <= 8; m <<= 1) { pa += __shfl_xor(pa, m); pd += __shfl_xor(pd, m); }
    if ((lane & 15) == 0) {
        int g = lane >> 4;
        as_out[wid * 4 + g] = pa; ad_out[wid * 4 + g] = pd;
    }
}

// ---------------------------------------------------------------------------
// CSR build over dst
// ---------------------------------------------------------------------------
__global__ void count_edges(const int* __restrict__ eidx, int* __restrict__ counts)
{
    int idx = blockIdx.x * 256 + threadIdx.x;
    if (idx >= TE_) return;
    int t = idx / E_, e = idx - t * E_;
    int d = eidx[(size_t)t * 2 * E_ + E_ + e];
    atomicAdd(&counts[t * N_ + d], 1);
}

__global__ __launch_bounds__(1024) void scan_per_t(
    const int* __restrict__ counts, int* __restrict__ rowptr, int* __restrict__ cursor)
{
    const int CH = 10;
    int t = blockIdx.x, i = threadIdx.x;
    int base0 = t * N_;
    int cnt[CH];
    int s = 0;
    int g0 = i * CH;
    #pragma unroll
    for (int q = 0; q < CH; ++q) {
        int g = g0 + q;
        cnt[q] = (g < N_) ? counts[base0 + g] : 0;
        s += cnt[q];
    }
    __shared__ int buf[1024];
    buf[i] = s;
    __syncthreads();
    for (int off = 1; off < 1024; off <<= 1) {
        int v = (i >= off) ? buf[i - off] : 0;
        __syncthreads();
        buf[i] += v;
        __syncthreads();
    }
    int run = t * E_ + buf[i] - s;
    #pragma unroll
    for (int q = 0; q < CH; ++q) {
        int g = g0 + q;
        if (g < N_) {
            rowptr[base0 + g] = run;
            cursor[base0 + g] = run;
            run += cnt[q];
        }
    }
    if (t == T_ - 1 && i == 1023) rowptr[T_ * N_] = TE_;
}

__global__ void fill_csr(const int* __restrict__ eidx, const float* __restrict__ ew,
                         int* __restrict__ cursor, int* __restrict__ src_csr,
                         float* __restrict__ ew_csr)
{
    int idx = blockIdx.x * 256 + threadIdx.x;
    if (idx >= TE_) return;
    int t = idx / E_, e = idx - t * E_;
    int s = eidx[(size_t)t * 2 * E_ + e];
    int d = eidx[(size_t)t * 2 * E_ + E_ + e];
    float w = ew[(size_t)t * E_ + e];
    int pos = atomicAdd(&cursor[t * N_ + d], 1);
    src_csr[pos] = t * N_ + s;
    ew_csr[pos] = w;
}

// ---------------------------------------------------------------------------
// GAT aggregation (single pass: softmax max-shift cancels exactly in num/den
// and exp args are bounded ~|0.5|, so no overflow). bf16 h in, bf16 out.
// ---------------------------------------------------------------------------
__global__ __launch_bounds__(256) void gat_node_128(
    const ushort* __restrict__ h, const float* __restrict__ as,
    const float* __restrict__ ad, const int* __restrict__ rowptr,
    const int* __restrict__ src_csr, const float* __restrict__ ew_csr,
    ushort* __restrict__ outp, int rows)
{
    int wid  = (blockIdx.x * 256 + threadIdx.x) >> 6;
    int lane = threadIdx.x & 63;
    if (wid >= rows) return;
    int start = rowptr[wid], end = rowptr[wid + 1];
    int h0 = lane >> 5, h1 = 2 + h0;
    float ad0 = ad[wid * 4 + h0], ad1 = ad[wid * 4 + h1];
    float acc0 = 0.f, acc1 = 0.f, den0 = 0.f, den1 = 0.f;
    for (int p = start; p < end; ++p) {
        int s = src_csr[p];
        float w = ew_csr[p];
        float e0 = as[s * 4 + h0] + ad0; e0 = e0 > 0.f ? e0 : 0.2f * e0;
        float e1 = as[s * 4 + h1] + ad1; e1 = e1 > 0.f ? e1 : 0.2f * e1;
        float x0 = __expf(e0) * w;
        float x1 = __expf(e1) * w;
        den0 += x0; den1 += x1;
        const ushort* hs = h + (size_t)s * 128;
        acc0 += x0 * bf2f(hs[lane]);
        acc1 += x1 * bf2f(hs[64 + lane]);
    }
    float o0 = acc0 / (den0 + 1e-16f);
    float o1 = acc1 / (den1 + 1e-16f);
    o0 = o0 > 0.f ? o0 : (__expf(o0) - 1.f);
    o1 = o1 > 0.f ? o1 : (__expf(o1) - 1.f);
    outp[(size_t)wid * 128 + lane]      = f2bf(o0);
    outp[(size_t)wid * 128 + 64 + lane] = f2bf(o1);
}

__global__ __launch_bounds__(256) void gat_node_64(
    const ushort* __restrict__ h, const float* __restrict__ as,
    const float* __restrict__ ad, const int* __restrict__ rowptr,
    const int* __restrict__ src_csr, const float* __restrict__ ew_csr,
    ushort* __restrict__ outp, int rows)
{
    int wid  = (blockIdx.x * 256 + threadIdx.x) >> 6;
    int lane = threadIdx.x & 63;
    if (wid >= rows) return;
    int start = rowptr[wid], end = rowptr[wid + 1];
    int hh = lane >> 4;
    float adv = ad[wid * 4 + hh];
    float acc = 0.f, den = 0.f;
    for (int p = start; p < end; ++p) {
        int s = src_csr[p];
        float w = ew_csr[p];
        float e = as[s * 4 + hh] + adv; e = e > 0.f ? e : 0.2f * e;
        float x = __expf(e) * w;
        den += x;
        acc += x * bf2f(h[(size_t)s * 64 + lane]);
    }
    float o = acc / (den + 1e-16f);
    o = o > 0.f ? o : (__expf(o) - 1.f);
    outp[(size_t)wid * 64 + lane] = f2bf(o);
}

// ---------------------------------------------------------------------------
// Meso pooling + agg assembly (g2 in bf16, agg out bf16)
// ---------------------------------------------------------------------------
__global__ __launch_bounds__(256) void meso_acc(
    const ushort* __restrict__ g2, const int* __restrict__ part,
    const float* __restrict__ Dw, float* __restrict__ msum, float* __restrict__ mden)
{
    int wid  = (blockIdx.x * 256 + threadIdx.x) >> 6;
    int lane = threadIdx.x & 63;
    if (wid >= TN_) return;
    int t = wid / N_;
    int p = part[wid];
    float dv = Dw[wid];
    atomicAdd(&msum[((size_t)(t * NC_ + p) << 6) + lane], dv * bf2f(g2[(size_t)wid * 64 + lane]));
    if (lane == 0) atomicAdd(&mden[t * NC_ + p], dv);
}

__global__ void agg_assemble(
    const ushort* __restrict__ g2, const int* __restrict__ part,
    const float* __restrict__ msum, const float* __restrict__ mden,
    ushort* __restrict__ agg)
{
    int idx = blockIdx.x * 256 + threadIdx.x;   // < TN*128
    int row = idx >> 7, d = idx & 127;
    ushort v;
    if (d < 64) {
        v = g2[(size_t)row * 64 + d];
    } else {
        int t = row / N_;
        int p = part[row];
        v = f2bf(msum[((size_t)(t * NC_ + p) << 6) + (d - 64)] / (mden[t * NC_ + p] + 1e-16f));
    }
    agg[idx] = v;
}

// ---------------------------------------------------------------------------
// LSTM cell: z (N x 512 fp32), c fp32 in-place, h out bf16 (row stride 128)
// ---------------------------------------------------------------------------
__global__ void lstm_cell(const float* __restrict__ z, float* __restrict__ c,
                          ushort* __restrict__ hb)
{
    int idx = blockIdx.x * 256 + threadIdx.x;   // < N*128
    int n = idx >> 7, j = idx & 127;
    const float* zr = z + (size_t)n * 512;
    float zi = zr[j], zf = zr[128 + j], zg = zr[256 + j], zo = zr[384 + j];
    float si = fast_sigmoid(zi);
    float sf = fast_sigmoid(zf);
    float so = fast_sigmoid(zo);
    float cn = sf * c[idx] + si * fast_tanh(zg);
    c[idx] = cn;
    hb[(size_t)n * 128 + j] = f2bf(so * fast_tanh(cn));
}

// ---------------------------------------------------------------------------
// Column sum-of-squares for emb (fp32), then normalize -> bf16 + per-row sq
// ---------------------------------------------------------------------------
__global__ __launch_bounds__(256) void col_sumsq(const float* __restrict__ emb,
                                                 float* __restrict__ colss)
{
    int tid = threadIdx.x;
    int col = tid & 63, rq = tid >> 6;
    float s = 0.f;
    for (int r = blockIdx.x * 4 + rq; r < N_; r += 40 * 4) {
        float v = emb[(size_t)r * 64 + col];
        s += v * v;
    }
    __shared__ float red[256];
    red[tid] = s;
    __syncthreads();
    if (tid < 64)
        atomicAdd(&colss[tid], red[tid] + red[tid + 64] + red[tid + 128] + red[tid + 192]);
}

// sq computed from the bf16-ROUNDED values so the i==j cancellation in the
// final dist is exact.
__global__ __launch_bounds__(256) void norm_rows(const float* __restrict__ emb,
                                                 const float* __restrict__ colss,
                                                 ushort* __restrict__ embb,
                                                 float* __restrict__ sq, int rows)
{
    int wid  = (blockIdx.x * 256 + threadIdx.x) >> 6;
    int lane = threadIdx.x & 63;
    if (wid >= rows) return;
    float nv = emb[(size_t)wid * 64 + lane] / sqrtf(colss[lane]);
    ushort ub = f2bf(nv);
    embb[(size_t)wid * 64 + lane] = ub;
    float nq = bf2f(ub);
    float q = nq * nq;
    #pragma unroll
    for (int m = 1; m <= 32; m <<= 1) q += __shfl_xor(q, m);
    if (lane == 0) sq[wid] = q;
}

// ---------------------------------------------------------------------------
// Fused final, MFMA: S = scal.scal^T, G = emb.emb^T (K=64, bf16),
// out = 1 + tanh((2G - sq_i - sq_j) * S). Block 128x128 (4 waves, 64x64 each).
// G and S are SYMMETRIC, so we swap MFMA operand order: the accumulator
// fragment's register quad then holds 4 CONSECUTIVE COLUMNS (j) at a fixed
// row i = bi + rt*16 + l16 (bitwise-identical values: bf16 products are exact
// in fp32 and the accumulation tree is unchanged). This turns the epilogue
// into float4 (dwordx4) nontemporal stores: 16 rows x 64B contiguous per
// store instruction, 4x fewer stores, full-line write combining (the old
// per-dword layout gave 1.41x write amplification and a 1.4 TB/s NT write
// stream -- the kernel's entire 404us was stall on that path).
// emb/scal/sq padded to NPAD_ rows (poison pad, stores guarded).
// ---------------------------------------------------------------------------
__global__ __launch_bounds__(256) void final_adj_mfma(
    const ushort* __restrict__ embb, const ushort* __restrict__ scalb,
    const float* __restrict__ sq, float* __restrict__ outp)
{
    int w = threadIdx.x >> 6, lane = threadIdx.x & 63;
    int quad = lane >> 4, l16 = lane & 15;
    int bi = blockIdx.y * 128 + (w >> 1) * 64;
    int bj = blockIdx.x * 128 + (w & 1) * 64;
    f32x4 zf = {0.f, 0.f, 0.f, 0.f};
    f32x4 accS[4][4], accG[4][4];
    #pragma unroll
    for (int rt = 0; rt < 4; ++rt)
        #pragma unroll
        for (int ct = 0; ct < 4; ++ct) { accS[rt][ct] = zf; accG[rt][ct] = zf; }

    #pragma unroll
    for (int ks = 0; ks < 2; ++ks) {
        int k0 = ks * 32 + quad * 8;
        bf16x8 ae[4], af[4], be[4], bs[4];
        #pragma unroll
        for (int t = 0; t < 4; ++t) {
            int ri = bi + t * 16 + l16;
            int rj = bj + t * 16 + l16;
            ae[t] = *(const bf16x8*)(embb  + (size_t)ri * 64 + k0);
            af[t] = *(const bf16x8*)(scalb + (size_t)ri * 64 + k0);
            be[t] = *(const bf16x8*)(embb  + (size_t)rj * 64 + k0);
            bs[t] = *(const bf16x8*)(scalb + (size_t)rj * 64 + k0);
        }
        // Swapped operand order: A-operand = bj-side rows, B-operand = bi-side
        // rows.  D's "col" (lane&15) dim -> i, D's "row" (quad*4+reg) dim -> j.
        #pragma unroll
        for (int rt = 0; rt < 4; ++rt)
            #pragma unroll
            for (int ct = 0; ct < 4; ++ct) {
                accG[rt][ct] = __builtin_amdgcn_mfma_f32_16x16x32_bf16(be[ct], ae[rt], accG[rt][ct], 0, 0, 0);
                accS[rt][ct] = __builtin_amdgcn_mfma_f32_16x16x32_bf16(bs[ct], af[rt], accS[rt][ct], 0, 0, 0);
            }
    }

    #pragma unroll
    for (int rt = 0; rt < 4; ++rt) {
        int i = bi + rt * 16 + l16;
        if (i >= N_) continue;
        float sqi = sq[i];
        #pragma unroll
        for (int ct = 0; ct < 4; ++ct) {
            int j0 = bj + ct * 16 + quad * 4;
            if (j0 >= N_) continue;               // N_%4==0: group all-in or all-out
            const float4 sj = *(const float4*)(sq + j0);
            float sjr[4] = { sj.x, sj.y, sj.z, sj.w };
            f32x4 v;
            #pragma unroll
            for (int r = 0; r < 4; ++r) {
                float G = accG[rt][ct][r], S = accS[rt][ct][r];
                float dist = 2.f * G - sqi - sjr[r];
                // 1 + tanh(y) = 2 - 2/(e^{2y}+1), inf-safe
                float t = __expf(2.f * dist * S);
                v[r] = 2.f - 2.f / (t + 1.f);
            }
            __builtin_nontemporal_store(v, (f32x4*)(outp + (size_t)i * N_ + j0));
        }
    }
}

// ---------------------------------------------------------------------------
extern "C" void kernel_launch(void* const* d_in, const int* in_sizes, int n_in,
                              void* d_out, int out_size, void* d_ws, size_t ws_size,
                              hipStream_t stream)
{
    (void)in_sizes; (void)n_in; (void)out_size; (void)ws_size;
    const float* feat    = (const float*)d_in[0];
    const float* eweight = (const float*)d_in[1];
    const float* Dw      = (const float*)d_in[2];
    const float* W1      = (const float*)d_in[3];
    const float* a_src1  = (const float*)d_in[4];
    const float* a_dst1  = (const float*)d_in[5];
    const float* W2      = (const float*)d_in[6];
    const float* a_src2  = (const float*)d_in[7];
    const float* a_dst2  = (const float*)d_in[8];
    const float* Wx      = (const float*)d_in[9];
    const float* Wh      = (const float*)d_in[10];
    const float* b_lstm  = (const float*)d_in[11];
    const float* emb_W   = (const float*)d_in[12];
    const float* emb_b   = (const float*)d_in[13];
    const float* scal_W  = (const float*)d_in[14];
    const float* scal_b  = (const float*)d_in[15];
    const int*   eidx    = (const int*)d_in[16];
    const int*   part    = (const int*)d_in[17];

    // ---- scratch layout (floats) inside d_out (dead before final_adj) ----
    float* out = (float*)d_out;
    ushort* h1b   = (ushort*)(out + 0);          // 80000x128 bf16 (5,120,000 f)
    ushort* g1b   = (ushort*)(out + 5120000);    // 80000x128 bf16
    ushort* h2b   = (ushort*)(out + 10240000);   // 80000x64 bf16
    ushort* g2b   = (ushort*)(out + 12800000);   // 80000x64 bf16
    float* as1    = out + 15360000;              // TN*4
    float* ad1    = out + 15680000;
    float* as2    = out + 16000000;
    float* ad2    = out + 16320000;
    int*   rowptr = (int*)(out + 16640000);      // TN+1
    int*   cursor = (int*)(out + 16720064);
    int*   counts = (int*)(out + 16800064);
    int*   src_csr= (int*)(out + 16880064);      // TE
    float* ew_csr = out + 19440064;              // TE
    float* msum   = out + 22000064;              // T*100*64
    float* mden   = out + 22051264;              // T*100
    ushort* aggb  = (ushort*)(out + 22052064);   // 80000x128 bf16
    float* ZX     = out + 27172064;              // 80000x512 fp32
    float* zbuf   = out + 68132064;              // 10000x512 fp32
    float* cstate = out + 73252064;              // 10000x128 fp32
    ushort* hbf   = (ushort*)(out + 74532064);   // NPAD x128 bf16 (647,168 f)
    ushort* featb = (ushort*)(out + 75179232);   // 80000x128 bf16
    ushort* W1T   = (ushort*)(out + 80299232);   // 128x128
    ushort* W2T   = (ushort*)(out + 80307424);   // 64x128
    ushort* WxT   = (ushort*)(out + 80311520);   // 512x128
    ushort* WhT   = (ushort*)(out + 80344288);   // 512x128
    ushort* eWT   = (ushort*)(out + 80377056);   // 64x128
    ushort* sWT   = (ushort*)(out + 80381152);   // 64x128
    float* embf   = out + 80385248;              // 10000x64 fp32
    float* colss  = out + 81025248;              // 64

    // ---- live-at-final buffers in d_ws ----
    ushort* embb  = (ushort*)d_ws;               // NPAD x 64 bf16
    ushort* scalb = embb + (size_t)NPAD_ * 64;   // NPAD x 64 bf16
    float*  sq    = (float*)(scalb + (size_t)NPAD_ * 64);  // NPAD fp32

    // ---- zero-init accumulation targets ----
    hipMemsetAsync(counts, 0, TN_ * sizeof(int), stream);
    hipMemsetAsync(msum, 0, (T_ * NC_ * 64 + T_ * NC_) * sizeof(float), stream);
    hipMemsetAsync(cstate, 0, (size_t)N_ * DR_ * sizeof(float), stream);
    hipMemsetAsync(hbf, 0, (size_t)NPAD_ * DR_ * sizeof(ushort), stream);  // h0 = 0 (+pad)
    hipMemsetAsync(colss, 0, 64 * sizeof(float), stream);

    // ---- converts ----
    conv_feat<<<5000, 256, 0, stream>>>(feat, featb, TN_ * F_ / 8);
    conv_weights<<<672, 256, 0, stream>>>(W1, W2, Wx, Wh, emb_W, scal_W,
                                          W1T, W2T, WxT, WhT, eWT, sWT);

    // ---- GAT layer 1 (batched over T) ----
    gemm_bf16<<<dim3(2, 625), 256, 0, stream>>>(featb, W1T, nullptr, h1b, nullptr, nullptr, TN_, 128, 128, 0);
    att_vec128<<<TN_/4, 256, 0, stream>>>(h1b, a_src1, a_dst1, as1, ad1, TN_);
    count_edges<<<(TE_+255)/256, 256, 0, stream>>>(eidx, counts);
    scan_per_t<<<T_, 1024, 0, stream>>>(counts, rowptr, cursor);
    fill_csr<<<(TE_+255)/256, 256, 0, stream>>>(eidx, eweight, cursor, src_csr, ew_csr);
    gat_node_128<<<TN_/4, 256, 0, stream>>>(h1b, as1, ad1, rowptr, src_csr, ew_csr, g1b, TN_);

    // ---- GAT layer 2 ----
    gemm_bf16<<<dim3(1, 625), 256, 0, stream>>>(g1b, W2T, nullptr, h2b, nullptr, nullptr, TN_, 128, 64, 0);
    att_vec64<<<TN_/4, 256, 0, stream>>>(h2b, a_src2, a_dst2, as2, ad2, TN_);
    gat_node_64<<<TN_/4, 256, 0, stream>>>(h2b, as2, ad2, rowptr, src_csr, ew_csr, g2b, TN_);

    // ---- meso + agg ----
    meso_acc<<<TN_/4, 256, 0, stream>>>(g2b, part, Dw, msum, mden);
    agg_assemble<<<TN_*128/256, 256, 0, stream>>>(g2b, part, msum, mden, aggb);

    // ---- LSTM: batched input projection, then 8-step recurrence ----
    gemm_bf16<<<dim3(8, 625), 256, 0, stream>>>(aggb, WxT, ZX, nullptr, b_lstm, nullptr, TN_, 128, 512, 0);
    for (int t = 0; t < T_; ++t) {
        gemm_bf16<<<dim3(8, 79), 256, 0, stream>>>(hbf, WhT, zbuf, nullptr, nullptr,
                                                   ZX + (size_t)t * N_ * 512, N_, 128, 512, 0);
        lstm_cell<<<N_*DR_/256, 256, 0, stream>>>(zbuf, cstate, hbf);
    }

    // ---- decoder heads ----
    gemm_bf16<<<dim3(1, 79), 256, 0, stream>>>(hbf, eWT, embf, nullptr, emb_b, nullptr, N_, 128, 64, 1);
    gemm_bf16<<<dim3(1, 79), 256, 0, stream>>>(hbf, sWT, nullptr, scalb, scal_b, nullptr, N_, 128, 64, 2);
    col_sumsq<<<40, 256, 0, stream>>>(embf, colss);
    norm_rows<<<(N_+3)/4, 256, 0, stream>>>(embf, colss, embb, sq, N_);

    // ---- fused final ----
    final_adj_mfma<<<dim3(79, 79), 256, 0, stream>>>(embb, scalb, sq, out);
}

// Round 2
// 1870.437 us; speedup vs baseline: 1.1174x; 1.0437x over previous
//
#include <hip/hip_runtime.h>
#include <cstddef>
#include <cstdint>

// Problem constants (fixed by setup_inputs)
#define T_   8
#define N_   10000
#define E_   320000
#define F_   128
#define D1_  128
#define D2_  64
#define DR_  128
#define NC_  100
#define TN_  (T_*N_)
#define TE_  (T_*E_)
#define NPAD_ 10112   // 79*128, row padding for M=10000 MFMA tiles

typedef __attribute__((ext_vector_type(8))) short bf16x8;
typedef __attribute__((ext_vector_type(8))) ushort u16x8;
typedef __attribute__((ext_vector_type(4))) float f32x4;

__device__ __forceinline__ float bf2f(ushort u) {
    return __uint_as_float(((unsigned int)u) << 16);
}
__device__ __forceinline__ ushort f2bf(float f) {
    unsigned int u = __float_as_uint(f);
    unsigned int r = (u + 0x7FFFu + ((u >> 16) & 1u)) >> 16;   // RNE
    return (ushort)r;
}
// numerically safe fast tanh / sigmoid (inf-safe forms)
__device__ __forceinline__ float fast_tanh(float x) {
    float t = __expf(2.f * x);
    return 1.f - 2.f / (t + 1.f);
}
__device__ __forceinline__ float fast_sigmoid(float x) {
    return 1.f / (1.f + __expf(-x));
}

// ---------------------------------------------------------------------------
// fp32 -> bf16 bulk convert (feat). 8 elems/thread.
// ---------------------------------------------------------------------------
__global__ __launch_bounds__(256) void conv_feat(const float* __restrict__ src,
                                                 ushort* __restrict__ dst, int n8)
{
    int idx = blockIdx.x * 256 + threadIdx.x;
    if (idx >= n8) return;
    const float4* s = (const float4*)src + (size_t)idx * 2;
    float4 x = s[0], y = s[1];
    u16x8 o;
    o[0]=f2bf(x.x); o[1]=f2bf(x.y); o[2]=f2bf(x.z); o[3]=f2bf(x.w);
    o[4]=f2bf(y.x); o[5]=f2bf(y.y); o[6]=f2bf(y.z); o[7]=f2bf(y.w);
    *((u16x8*)dst + idx) = o;
}

// ---------------------------------------------------------------------------
// All weights -> transposed bf16 (BT[n][k] = W[k][n]) in one launch.
// Segments: W1 128x128, W2 128x64, Wx 128x512, Wh 128x512, eW 128x64, sW 128x64
// ---------------------------------------------------------------------------
__global__ __launch_bounds__(256) void conv_weights(
    const float* __restrict__ W1, const float* __restrict__ W2,
    const float* __restrict__ Wx, const float* __restrict__ Wh,
    const float* __restrict__ eW, const float* __restrict__ sW,
    ushort* __restrict__ W1T, ushort* __restrict__ W2T,
    ushort* __restrict__ WxT, ushort* __restrict__ WhT,
    ushort* __restrict__ eWT, ushort* __restrict__ sWT)
{
    int idx = blockIdx.x * 256 + threadIdx.x;
    if (idx < 16384)       { int n=idx>>7,   k=idx&127;            W1T[idx]=f2bf(W1[k*128+n]); }
    else if (idx < 24576)  { int l=idx-16384;  int n=l>>7,k=l&127; W2T[l]=f2bf(W2[k*64+n]); }
    else if (idx < 90112)  { int l=idx-24576;  int n=l>>7,k=l&127; WxT[l]=f2bf(Wx[k*512+n]); }
    else if (idx < 155648) { int l=idx-90112;  int n=l>>7,k=l&127; WhT[l]=f2bf(Wh[k*512+n]); }
    else if (idx < 163840) { int l=idx-155648; int n=l>>7,k=l&127; eWT[l]=f2bf(eW[k*64+n]); }
    else if (idx < 172032) { int l=idx-163840; int n=l>>7,k=l&127; sWT[l]=f2bf(sW[k*64+n]); }
}

// ---------------------------------------------------------------------------
// bf16 MFMA GEMM: C[M x Nc] = A[M x K] @ BT[Nc x K]^T  (+bias) (+addsrc) (act)
// K % 32 == 0, Nc % 64 == 0. Block 256 thr = 4 waves; tile 128 x 64; each wave
// computes 32 x 64 (2x4 tiles of 16x16, mfma_f32_16x16x32_bf16).
// A rows beyond M must be readable (caller pads allocations).
// act: 0 none, 1 tanh, 2 sigmoid.  Output to Cf (fp32) and/or Cb (bf16).
// ---------------------------------------------------------------------------
__global__ __launch_bounds__(256) void gemm_bf16(
    const ushort* __restrict__ A, const ushort* __restrict__ BT,
    float* __restrict__ Cf, ushort* __restrict__ Cb,
    const float* __restrict__ bias, const float* __restrict__ addsrc,
    int M, int K, int Nc, int act)
{
    int w = threadIdx.x >> 6, lane = threadIdx.x & 63;
    int quad = lane >> 4, l16 = lane & 15;
    int m0 = blockIdx.y * 128 + w * 32;
    int n0 = blockIdx.x * 64;
    f32x4 zf = {0.f, 0.f, 0.f, 0.f};
    f32x4 acc[2][4];
    #pragma unroll
    for (int rt = 0; rt < 2; ++rt)
        #pragma unroll
        for (int ct = 0; ct < 4; ++ct) acc[rt][ct] = zf;

    for (int k0 = 0; k0 < K; k0 += 32) {
        int kk = k0 + quad * 8;
        bf16x8 a0 = *(const bf16x8*)(A + (size_t)(m0 + l16) * K + kk);
        bf16x8 a1 = *(const bf16x8*)(A + (size_t)(m0 + 16 + l16) * K + kk);
        bf16x8 b[4];
        #pragma unroll
        for (int ct = 0; ct < 4; ++ct)
            b[ct] = *(const bf16x8*)(BT + (size_t)(n0 + ct * 16 + l16) * K + kk);
        #pragma unroll
        for (int ct = 0; ct < 4; ++ct) {
            acc[0][ct] = __builtin_amdgcn_mfma_f32_16x16x32_bf16(a0, b[ct], acc[0][ct], 0, 0, 0);
            acc[1][ct] = __builtin_amdgcn_mfma_f32_16x16x32_bf16(a1, b[ct], acc[1][ct], 0, 0, 0);
        }
    }

    #pragma unroll
    for (int rt = 0; rt < 2; ++rt) {
        int ibase = m0 + rt * 16 + quad * 4;
        #pragma unroll
        for (int r = 0; r < 4; ++r) {
            int i = ibase + r;
            if (i >= M) continue;
            #pragma unroll
            for (int ct = 0; ct < 4; ++ct) {
                int j = n0 + ct * 16 + l16;
                float v = acc[rt][ct][r];
                if (bias)   v += bias[j];
                if (addsrc) v += addsrc[(size_t)i * Nc + j];
                if (act == 1)      v = fast_tanh(v);
                else if (act == 2) v = fast_sigmoid(v);
                if (Cf) Cf[(size_t)i * Nc + j] = v;
                if (Cb) Cb[(size_t)i * Nc + j] = f2bf(v);
            }
        }
    }
}

// ---------------------------------------------------------------------------
// Per-node attention dots (bf16 h). One wave per row.
// ---------------------------------------------------------------------------
__global__ __launch_bounds__(256) void att_vec128(
    const ushort* __restrict__ h, const float* __restrict__ a_src,
    const float* __restrict__ a_dst, float* __restrict__ as_out,
    float* __restrict__ ad_out, int rows)
{
    int wid  = (blockIdx.x * 256 + threadIdx.x) >> 6;
    int lane = threadIdx.x & 63;
    if (wid >= rows) return;
    const ushort* hr = h + (size_t)wid * 128;
    float v0 = bf2f(hr[lane]), v1 = bf2f(hr[64 + lane]);
    float pa0 = v0 * a_src[lane], pa1 = v1 * a_src[64 + lane];
    float pd0 = v0 * a_dst[lane], pd1 = v1 * a_dst[64 + lane];
    #pragma unroll
    for (int m = 1; m <= 16; m <<= 1) {
        pa0 += __shfl_xor(pa0, m); pa1 += __shfl_xor(pa1, m);
        pd0 += __shfl_xor(pd0, m); pd1 += __shfl_xor(pd1, m);
    }
    if ((lane & 31) == 0) {
        int g = lane >> 5;
        as_out[wid * 4 + g] = pa0; as_out[wid * 4 + 2 + g] = pa1;
        ad_out[wid * 4 + g] = pd0; ad_out[wid * 4 + 2 + g] = pd1;
    }
}

__global__ __launch_bounds__(256) void att_vec64(
    const ushort* __restrict__ h, const float* __restrict__ a_src,
    const float* __restrict__ a_dst, float* __restrict__ as_out,
    float* __restrict__ ad_out, int rows)
{
    int wid  = (blockIdx.x * 256 + threadIdx.x) >> 6;
    int lane = threadIdx.x & 63;
    if (wid >= rows) return;
    float v = bf2f(h[(size_t)wid * 64 + lane]);
    float pa = v * a_src[lane], pd = v * a_dst[lane];
    #pragma unroll
    for (int m = 1; m <= 8; m <<= 1) { pa += __shfl_xor(pa, m); pd += __shfl_xor(pd, m); }
    if ((lane & 15) == 0) {
        int g = lane >> 4;
        as_out[wid * 4 + g] = pa; ad_out[wid * 4 + g] = pd;
    }
}

// ---------------------------------------------------------------------------
// CSR build over dst
// ---------------------------------------------------------------------------
__global__ void count_edges(const int* __restrict__ eidx, int* __restrict__ counts)
{
    int idx = blockIdx.x * 256 + threadIdx.x;
    if (idx >= TE_) return;
    int t = idx / E_, e = idx - t * E_;
    int d = eidx[(size_t)t * 2 * E_ + E_ + e];
    atomicAdd(&counts[t * N_ + d], 1);
}

__global__ __launch_bounds__(1024) void scan_per_t(
    const int* __restrict__ counts, int* __restrict__ rowptr, int* __restrict__ cursor)
{
    const int CH = 10;
    int t = blockIdx.x, i = threadIdx.x;
    int base0 = t * N_;
    int cnt[CH];
    int s = 0;
    int g0 = i * CH;
    #pragma unroll
    for (int q = 0; q < CH; ++q) {
        int g = g0 + q;
        cnt[q] = (g < N_) ? counts[base0 + g] : 0;
        s += cnt[q];
    }
    __shared__ int buf[1024];
    buf[i] = s;
    __syncthreads();
    for (int off = 1; off < 1024; off <<= 1) {
        int v = (i >= off) ? buf[i - off] : 0;
        __syncthreads();
        buf[i] += v;
        __syncthreads();
    }
    int run = t * E_ + buf[i] - s;
    #pragma unroll
    for (int q = 0; q < CH; ++q) {
        int g = g0 + q;
        if (g < N_) {
            rowptr[base0 + g] = run;
            cursor[base0 + g] = run;
            run += cnt[q];
        }
    }
    if (t == T_ - 1 && i == 1023) rowptr[T_ * N_] = TE_;
}

__global__ void fill_csr(const int* __restrict__ eidx, const float* __restrict__ ew,
                         int* __restrict__ cursor, int* __restrict__ src_csr,
                         float* __restrict__ ew_csr)
{
    int idx = blockIdx.x * 256 + threadIdx.x;
    if (idx >= TE_) return;
    int t = idx / E_, e = idx - t * E_;
    int s = eidx[(size_t)t * 2 * E_ + e];
    int d = eidx[(size_t)t * 2 * E_ + E_ + e];
    float w = ew[(size_t)t * E_ + e];
    int pos = atomicAdd(&cursor[t * N_ + d], 1);
    src_csr[pos] = t * N_ + s;
    ew_csr[pos] = w;
}

// ---------------------------------------------------------------------------
// GAT aggregation (single pass: softmax max-shift cancels exactly in num/den
// and exp args are bounded ~|0.5|, so no overflow). bf16 h in, bf16 out.
// ---------------------------------------------------------------------------
__global__ __launch_bounds__(256) void gat_node_128(
    const ushort* __restrict__ h, const float* __restrict__ as,
    const float* __restrict__ ad, const int* __restrict__ rowptr,
    const int* __restrict__ src_csr, const float* __restrict__ ew_csr,
    ushort* __restrict__ outp, int rows)
{
    int wid  = (blockIdx.x * 256 + threadIdx.x) >> 6;
    int lane = threadIdx.x & 63;
    if (wid >= rows) return;
    int start = rowptr[wid], end = rowptr[wid + 1];
    int h0 = lane >> 5, h1 = 2 + h0;
    float ad0 = ad[wid * 4 + h0], ad1 = ad[wid * 4 + h1];
    float acc0 = 0.f, acc1 = 0.f, den0 = 0.f, den1 = 0.f;
    for (int p = start; p < end; ++p) {
        int s = src_csr[p];
        float w = ew_csr[p];
        float e0 = as[s * 4 + h0] + ad0; e0 = e0 > 0.f ? e0 : 0.2f * e0;
        float e1 = as[s * 4 + h1] + ad1; e1 = e1 > 0.f ? e1 : 0.2f * e1;
        float x0 = __expf(e0) * w;
        float x1 = __expf(e1) * w;
        den0 += x0; den1 += x1;
        const ushort* hs = h + (size_t)s * 128;
        acc0 += x0 * bf2f(hs[lane]);
        acc1 += x1 * bf2f(hs[64 + lane]);
    }
    float o0 = acc0 / (den0 + 1e-16f);
    float o1 = acc1 / (den1 + 1e-16f);
    o0 = o0 > 0.f ? o0 : (__expf(o0) - 1.f);
    o1 = o1 > 0.f ? o1 : (__expf(o1) - 1.f);
    outp[(size_t)wid * 128 + lane]      = f2bf(o0);
    outp[(size_t)wid * 128 + 64 + lane] = f2bf(o1);
}

__global__ __launch_bounds__(256) void gat_node_64(
    const ushort* __restrict__ h, const float* __restrict__ as,
    const float* __restrict__ ad, const int* __restrict__ rowptr,
    const int* __restrict__ src_csr, const float* __restrict__ ew_csr,
    ushort* __restrict__ outp, int rows)
{
    int wid  = (blockIdx.x * 256 + threadIdx.x) >> 6;
    int lane = threadIdx.x & 63;
    if (wid >= rows) return;
    int start = rowptr[wid], end = rowptr[wid + 1];
    int hh = lane >> 4;
    float adv = ad[wid * 4 + hh];
    float acc = 0.f, den = 0.f;
    for (int p = start; p < end; ++p) {
        int s = src_csr[p];
        float w = ew_csr[p];
        float e = as[s * 4 + hh] + adv; e = e > 0.f ? e : 0.2f * e;
        float x = __expf(e) * w;
        den += x;
        acc += x * bf2f(h[(size_t)s * 64 + lane]);
    }
    float o = acc / (den + 1e-16f);
    o = o > 0.f ? o : (__expf(o) - 1.f);
    outp[(size_t)wid * 64 + lane] = f2bf(o);
}

// ---------------------------------------------------------------------------
// Meso pooling + agg assembly (g2 in bf16, agg out bf16)
// ---------------------------------------------------------------------------
__global__ __launch_bounds__(256) void meso_acc(
    const ushort* __restrict__ g2, const int* __restrict__ part,
    const float* __restrict__ Dw, float* __restrict__ msum, float* __restrict__ mden)
{
    int wid  = (blockIdx.x * 256 + threadIdx.x) >> 6;
    int lane = threadIdx.x & 63;
    if (wid >= TN_) return;
    int t = wid / N_;
    int p = part[wid];
    float dv = Dw[wid];
    atomicAdd(&msum[((size_t)(t * NC_ + p) << 6) + lane], dv * bf2f(g2[(size_t)wid * 64 + lane]));
    if (lane == 0) atomicAdd(&mden[t * NC_ + p], dv);
}

__global__ void agg_assemble(
    const ushort* __restrict__ g2, const int* __restrict__ part,
    const float* __restrict__ msum, const float* __restrict__ mden,
    ushort* __restrict__ agg)
{
    int idx = blockIdx.x * 256 + threadIdx.x;   // < TN*128
    int row = idx >> 7, d = idx & 127;
    ushort v;
    if (d < 64) {
        v = g2[(size_t)row * 64 + d];
    } else {
        int t = row / N_;
        int p = part[row];
        v = f2bf(msum[((size_t)(t * NC_ + p) << 6) + (d - 64)] / (mden[t * NC_ + p] + 1e-16f));
    }
    agg[idx] = v;
}

// ---------------------------------------------------------------------------
// LSTM cell: z (N x 512 fp32), c fp32 in-place, h out bf16 (row stride 128)
// ---------------------------------------------------------------------------
__global__ void lstm_cell(const float* __restrict__ z, float* __restrict__ c,
                          ushort* __restrict__ hb)
{
    int idx = blockIdx.x * 256 + threadIdx.x;   // < N*128
    int n = idx >> 7, j = idx & 127;
    const float* zr = z + (size_t)n * 512;
    float zi = zr[j], zf = zr[128 + j], zg = zr[256 + j], zo = zr[384 + j];
    float si = fast_sigmoid(zi);
    float sf = fast_sigmoid(zf);
    float so = fast_sigmoid(zo);
    float cn = sf * c[idx] + si * fast_tanh(zg);
    c[idx] = cn;
    hb[(size_t)n * 128 + j] = f2bf(so * fast_tanh(cn));
}

// ---------------------------------------------------------------------------
// Column sum-of-squares for emb (fp32), then normalize -> bf16 + per-row sq
// ---------------------------------------------------------------------------
__global__ __launch_bounds__(256) void col_sumsq(const float* __restrict__ emb,
                                                 float* __restrict__ colss)
{
    int tid = threadIdx.x;
    int col = tid & 63, rq = tid >> 6;
    float s = 0.f;
    for (int r = blockIdx.x * 4 + rq; r < N_; r += 40 * 4) {
        float v = emb[(size_t)r * 64 + col];
        s += v * v;
    }
    __shared__ float red[256];
    red[tid] = s;
    __syncthreads();
    if (tid < 64)
        atomicAdd(&colss[tid], red[tid] + red[tid + 64] + red[tid + 128] + red[tid + 192]);
}

// sq computed from the bf16-ROUNDED values so the i==j cancellation in the
// final dist is exact.
__global__ __launch_bounds__(256) void norm_rows(const float* __restrict__ emb,
                                                 const float* __restrict__ colss,
                                                 ushort* __restrict__ embb,
                                                 float* __restrict__ sq, int rows)
{
    int wid  = (blockIdx.x * 256 + threadIdx.x) >> 6;
    int lane = threadIdx.x & 63;
    if (wid >= rows) return;
    float nv = emb[(size_t)wid * 64 + lane] / sqrtf(colss[lane]);
    ushort ub = f2bf(nv);
    embb[(size_t)wid * 64 + lane] = ub;
    float nq = bf2f(ub);
    float q = nq * nq;
    #pragma unroll
    for (int m = 1; m <= 32; m <<= 1) q += __shfl_xor(q, m);
    if (lane == 0) sq[wid] = q;
}

// ---------------------------------------------------------------------------
// Fused final, MFMA: S = scal.scal^T, G = emb.emb^T (K=64, bf16),
// out = 1 + tanh((2G - sq_i - sq_j) * S).
//
// Write-amplification analysis (round 1): out row stride = 40000 B = 64 mod
// 128, so ODD rows have cache lines at col = 16 mod 32 floats. The direct
// accumulator store layout (64B halves per instruction) left 2 uncombinable
// halves per odd row per 64-col wave tile -> 1.31x WRITE_SIZE and a ~2 TB/s
// effective NT write path.
//
// v3: block = 128-row band x 640 cols (5 j-tiles of 128), grid (16,79).
// Per j-tile: MFMA (swapped operands, symmetric G/S) -> epilogue -> LDS
// stage [128][132] -> copy-out where each row's 512 B is written by 32
// consecutive lanes of ONE dwordx4 NT store, SHIFTED -64 B for odd rows so
// every store covers exactly 4 full 128 B lines for both parities. The 16
// floats odd rows need from the previous j-tile live in a double-buffered
// LDS edge strip; a tiny flush pass writes the band's trailing 64 B.
// Remaining partials: band edges only (~1%).
// emb/scal/sq padded to NPAD_ rows (poison pad, stores guarded).
// ---------------------------------------------------------------------------
#define FTJ_   5
#define FCOLS_ (FTJ_*128)

__global__ __launch_bounds__(256) void final_adj_mfma(
    const ushort* __restrict__ embb, const ushort* __restrict__ scalb,
    const float* __restrict__ sq, float* __restrict__ outp)
{
    __shared__ float cur[128][132];      // 128x128 tile, +4 pad: conflict-free b128
    __shared__ float edg[2][64][16];     // odd local rows' cols [112,128) of tile t

    int w = threadIdx.x >> 6, lane = threadIdx.x & 63;
    int quad = lane >> 4, l16 = lane & 15;
    int bi = blockIdx.y * 128;
    int Wb = blockIdx.x * FCOLS_;
    int wi = bi + (w >> 1) * 64;         // wave row base (global)

    // row-side sq, persistent (pad rows read garbage; stores guarded)
    float sqi[4];
    #pragma unroll
    for (int rt = 0; rt < 4; ++rt) sqi[rt] = sq[wi + rt * 16 + l16];

    int tLast = (N_ - 1 - Wb) / 128;
    if (tLast > FTJ_ - 1) tLast = FTJ_ - 1;

    for (int t = 0; t <= tLast; ++t) {
        int Wt = Wb + t * 128;
        int wj = Wt + (w & 1) * 64;      // wave col base (global)

        f32x4 zf = {0.f, 0.f, 0.f, 0.f};
        f32x4 accG[4][4], accS[4][4];
        #pragma unroll
        for (int rt = 0; rt < 4; ++rt)
            #pragma unroll
            for (int ct = 0; ct < 4; ++ct) { accG[rt][ct] = zf; accS[rt][ct] = zf; }

        #pragma unroll
        for (int ks = 0; ks < 2; ++ks) {
            int k0 = ks * 32 + quad * 8;
            bf16x8 ae[4], af[4], be[4], bs[4];
            #pragma unroll
            for (int q = 0; q < 4; ++q) {
                int ri = wi + q * 16 + l16;
                int rj = wj + q * 16 + l16;          // max 10111 < NPAD_
                ae[q] = *(const bf16x8*)(embb  + (size_t)ri * 64 + k0);
                af[q] = *(const bf16x8*)(scalb + (size_t)ri * 64 + k0);
                be[q] = *(const bf16x8*)(embb  + (size_t)rj * 64 + k0);
                bs[q] = *(const bf16x8*)(scalb + (size_t)rj * 64 + k0);
            }
            // Swapped operands (G,S symmetric): i = wave_row + rt*16 + l16,
            // j = wave_col + ct*16 + quad*4 + r  (bitwise-identical values).
            #pragma unroll
            for (int rt = 0; rt < 4; ++rt)
                #pragma unroll
                for (int ct = 0; ct < 4; ++ct) {
                    accG[rt][ct] = __builtin_amdgcn_mfma_f32_16x16x32_bf16(be[ct], ae[rt], accG[rt][ct], 0, 0, 0);
                    accS[rt][ct] = __builtin_amdgcn_mfma_f32_16x16x32_bf16(bs[ct], af[rt], accS[rt][ct], 0, 0, 0);
                }
        }

        __syncthreads();   // previous copy-out finished reading cur/edg

        // epilogue -> LDS stage (+edge save for next tile's odd-row heads)
        #pragma unroll
        for (int rt = 0; rt < 4; ++rt) {
            int li = (w >> 1) * 64 + rt * 16 + l16;
            float si = sqi[rt];
            #pragma unroll
            for (int ct = 0; ct < 4; ++ct) {
                int lj = (w & 1) * 64 + ct * 16 + quad * 4;
                const float4 sj = *(const float4*)(sq + Wt + lj);   // <= 10111 < NPAD_
                float sjr[4] = { sj.x, sj.y, sj.z, sj.w };
                f32x4 v;
                #pragma unroll
                for (int r = 0; r < 4; ++r) {
                    float G = accG[rt][ct][r], S = accS[rt][ct][r];
                    float dist = 2.f * G - si - sjr[r];
                    // 1 + tanh(y) = 2 - 2/(e^{2y}+1), inf-safe
                    float e = __expf(2.f * dist * S);
                    v[r] = 2.f - 2.f / (e + 1.f);
                }
                *(f32x4*)&cur[li][lj] = v;
                if ((w & 1) && ct == 3 && (li & 1))
                    *(f32x4*)&edg[t & 1][li >> 1][quad * 4] = v;
            }
        }

        __syncthreads();

        // copy-out: 16 passes x 8 rows; each row's 512 B from 32 consecutive
        // lanes, odd rows shifted -16 floats -> all stores are 4 full lines.
        // Wave w handles rows (lane>>5)*4 + w -> parity uniform per wave.
        int lane5 = lane & 31;
        #pragma unroll
        for (int pass = 0; pass < 16; ++pass) {
            int r = pass * 8 + (lane >> 5) * 4 + w;
            int i = bi + r;
            if (i < N_) {
                if (!(r & 1)) {
                    int gcol = Wt + lane5 * 4;
                    if (gcol < N_)
                        __builtin_nontemporal_store(*(const f32x4*)&cur[r][lane5 * 4],
                            (f32x4*)(outp + (size_t)i * N_ + gcol));
                } else {
                    int gcol = Wt - 16 + lane5 * 4;
                    // t==0, lane5<4: either out of range (bx==0) or owned by
                    // the left neighbor block's flush.
                    if ((t > 0 || lane5 >= 4) && gcol >= 0 && gcol < N_) {
                        f32x4 v;
                        if (lane5 < 4) v = *(const f32x4*)&edg[(t & 1) ^ 1][r >> 1][lane5 * 4];
                        else           v = *(const f32x4*)&cur[r][lane5 * 4 - 16];
                        __builtin_nontemporal_store(v,
                            (f32x4*)(outp + (size_t)i * N_ + gcol));
                    }
                }
            }
        }
    }

    // flush: trailing 16 cols of the band's last tile, odd rows (cur intact)
    {
        int tid = threadIdx.x;
        int r = ((tid >> 2) << 1) | 1;            // odd rows 1..127
        int k = (tid & 3) * 4;
        int i = bi + r;
        int gcol = Wb + tLast * 128 + 112 + k;
        if (i < N_ && gcol < N_) {
            f32x4 v = *(const f32x4*)&cur[r][112 + k];
            __builtin_nontemporal_store(v, (f32x4*)(outp + (size_t)i * N_ + gcol));
        }
    }
}

// ---------------------------------------------------------------------------
extern "C" void kernel_launch(void* const* d_in, const int* in_sizes, int n_in,
                              void* d_out, int out_size, void* d_ws, size_t ws_size,
                              hipStream_t stream)
{
    (void)in_sizes; (void)n_in; (void)out_size; (void)ws_size;
    const float* feat    = (const float*)d_in[0];
    const float* eweight = (const float*)d_in[1];
    const float* Dw      = (const float*)d_in[2];
    const float* W1      = (const float*)d_in[3];
    const float* a_src1  = (const float*)d_in[4];
    const float* a_dst1  = (const float*)d_in[5];
    const float* W2      = (const float*)d_in[6];
    const float* a_src2  = (const float*)d_in[7];
    const float* a_dst2  = (const float*)d_in[8];
    const float* Wx      = (const float*)d_in[9];
    const float* Wh      = (const float*)d_in[10];
    const float* b_lstm  = (const float*)d_in[11];
    const float* emb_W   = (const float*)d_in[12];
    const float* emb_b   = (const float*)d_in[13];
    const float* scal_W  = (const float*)d_in[14];
    const float* scal_b  = (const float*)d_in[15];
    const int*   eidx    = (const int*)d_in[16];
    const int*   part    = (const int*)d_in[17];

    // ---- scratch layout (floats) inside d_out (dead before final_adj) ----
    float* out = (float*)d_out;
    ushort* h1b   = (ushort*)(out + 0);          // 80000x128 bf16 (5,120,000 f)
    ushort* g1b   = (ushort*)(out + 5120000);    // 80000x128 bf16
    ushort* h2b   = (ushort*)(out + 10240000);   // 80000x64 bf16
    ushort* g2b   = (ushort*)(out + 12800000);   // 80000x64 bf16
    float* as1    = out + 15360000;              // TN*4
    float* ad1    = out + 15680000;
    float* as2    = out + 16000000;
    float* ad2    = out + 16320000;
    int*   rowptr = (int*)(out + 16640000);      // TN+1
    int*   cursor = (int*)(out + 16720064);
    int*   counts = (int*)(out + 16800064);
    int*   src_csr= (int*)(out + 16880064);      // TE
    float* ew_csr = out + 19440064;              // TE
    float* msum   = out + 22000064;              // T*100*64
    float* mden   = out + 22051264;              // T*100
    ushort* aggb  = (ushort*)(out + 22052064);   // 80000x128 bf16
    float* ZX     = out + 27172064;              // 80000x512 fp32
    float* zbuf   = out + 68132064;              // 10000x512 fp32
    float* cstate = out + 73252064;              // 10000x128 fp32
    ushort* hbf   = (ushort*)(out + 74532064);   // NPAD x128 bf16 (647,168 f)
    ushort* featb = (ushort*)(out + 75179232);   // 80000x128 bf16
    ushort* W1T   = (ushort*)(out + 80299232);   // 128x128
    ushort* W2T   = (ushort*)(out + 80307424);   // 64x128
    ushort* WxT   = (ushort*)(out + 80311520);   // 512x128
    ushort* WhT   = (ushort*)(out + 80344288);   // 512x128
    ushort* eWT   = (ushort*)(out + 80377056);   // 64x128
    ushort* sWT   = (ushort*)(out + 80381152);   // 64x128
    float* embf   = out + 80385248;              // 10000x64 fp32
    float* colss  = out + 81025248;              // 64

    // ---- live-at-final buffers in d_ws ----
    ushort* embb  = (ushort*)d_ws;               // NPAD x 64 bf16
    ushort* scalb = embb + (size_t)NPAD_ * 64;   // NPAD x 64 bf16
    float*  sq    = (float*)(scalb + (size_t)NPAD_ * 64);  // NPAD fp32

    // ---- zero-init accumulation targets ----
    hipMemsetAsync(counts, 0, TN_ * sizeof(int), stream);
    hipMemsetAsync(msum, 0, (T_ * NC_ * 64 + T_ * NC_) * sizeof(float), stream);
    hipMemsetAsync(cstate, 0, (size_t)N_ * DR_ * sizeof(float), stream);
    hipMemsetAsync(hbf, 0, (size_t)NPAD_ * DR_ * sizeof(ushort), stream);  // h0 = 0 (+pad)
    hipMemsetAsync(colss, 0, 64 * sizeof(float), stream);

    // ---- converts ----
    conv_feat<<<5000, 256, 0, stream>>>(feat, featb, TN_ * F_ / 8);
    conv_weights<<<672, 256, 0, stream>>>(W1, W2, Wx, Wh, emb_W, scal_W,
                                          W1T, W2T, WxT, WhT, eWT, sWT);

    // ---- GAT layer 1 (batched over T) ----
    gemm_bf16<<<dim3(2, 625), 256, 0, stream>>>(featb, W1T, nullptr, h1b, nullptr, nullptr, TN_, 128, 128, 0);
    att_vec128<<<TN_/4, 256, 0, stream>>>(h1b, a_src1, a_dst1, as1, ad1, TN_);
    count_edges<<<(TE_+255)/256, 256, 0, stream>>>(eidx, counts);
    scan_per_t<<<T_, 1024, 0, stream>>>(counts, rowptr, cursor);
    fill_csr<<<(TE_+255)/256, 256, 0, stream>>>(eidx, eweight, cursor, src_csr, ew_csr);
    gat_node_128<<<TN_/4, 256, 0, stream>>>(h1b, as1, ad1, rowptr, src_csr, ew_csr, g1b, TN_);

    // ---- GAT layer 2 ----
    gemm_bf16<<<dim3(1, 625), 256, 0, stream>>>(g1b, W2T, nullptr, h2b, nullptr, nullptr, TN_, 128, 64, 0);
    att_vec64<<<TN_/4, 256, 0, stream>>>(h2b, a_src2, a_dst2, as2, ad2, TN_);
    gat_node_64<<<TN_/4, 256, 0, stream>>>(h2b, as2, ad2, rowptr, src_csr, ew_csr, g2b, TN_);

    // ---- meso + agg ----
    meso_acc<<<TN_/4, 256, 0, stream>>>(g2b, part, Dw, msum, mden);
    agg_assemble<<<TN_*128/256, 256, 0, stream>>>(g2b, part, msum, mden, aggb);

    // ---- LSTM: batched input projection, then 8-step recurrence ----
    gemm_bf16<<<dim3(8, 625), 256, 0, stream>>>(aggb, WxT, ZX, nullptr, b_lstm, nullptr, TN_, 128, 512, 0);
    for (int t = 0; t < T_; ++t) {
        gemm_bf16<<<dim3(8, 79), 256, 0, stream>>>(hbf, WhT, zbuf, nullptr, nullptr,
                                                   ZX + (size_t)t * N_ * 512, N_, 128, 512, 0);
        lstm_cell<<<N_*DR_/256, 256, 0, stream>>>(zbuf, cstate, hbf);
    }

    // ---- decoder heads ----
    gemm_bf16<<<dim3(1, 79), 256, 0, stream>>>(hbf, eWT, embf, nullptr, emb_b, nullptr, N_, 128, 64, 1);
    gemm_bf16<<<dim3(1, 79), 256, 0, stream>>>(hbf, sWT, nullptr, scalb, scal_b, nullptr, N_, 128, 64, 2);
    col_sumsq<<<40, 256, 0, stream>>>(embf, colss);
    norm_rows<<<(N_+3)/4, 256, 0, stream>>>(embf, colss, embb, sq, N_);

    // ---- fused final ----
    final_adj_mfma<<<dim3(16, 79), 256, 0, stream>>>(embb, scalb, sq, out);
}

// Round 3
// 1639.587 us; speedup vs baseline: 1.2747x; 1.1408x over previous
//
#include <hip/hip_runtime.h>
#include <cstddef>
#include <cstdint>

// Problem constants (fixed by setup_inputs)
#define T_   8
#define N_   10000
#define E_   320000
#define F_   128
#define D1_  128
#define D2_  64
#define DR_  128
#define NC_  100
#define TN_  (T_*N_)
#define TE_  (T_*E_)
#define NPAD_ 10112   // 79*128, row padding for M=10000 MFMA tiles

typedef __attribute__((ext_vector_type(8))) short bf16x8;
typedef __attribute__((ext_vector_type(8))) ushort u16x8;
typedef __attribute__((ext_vector_type(4))) float f32x4;

__device__ __forceinline__ float bf2f(ushort u) {
    return __uint_as_float(((unsigned int)u) << 16);
}
__device__ __forceinline__ ushort f2bf(float f) {
    unsigned int u = __float_as_uint(f);
    unsigned int r = (u + 0x7FFFu + ((u >> 16) & 1u)) >> 16;   // RNE
    return (ushort)r;
}
// numerically safe fast tanh / sigmoid (inf-safe forms)
__device__ __forceinline__ float fast_tanh(float x) {
    float t = __expf(2.f * x);
    return 1.f - 2.f / (t + 1.f);
}
__device__ __forceinline__ float fast_sigmoid(float x) {
    return 1.f / (1.f + __expf(-x));
}

// ---------------------------------------------------------------------------
// fp32 -> bf16 bulk convert (feat). 8 elems/thread.
// ---------------------------------------------------------------------------
__global__ __launch_bounds__(256) void conv_feat(const float* __restrict__ src,
                                                 ushort* __restrict__ dst, int n8)
{
    int idx = blockIdx.x * 256 + threadIdx.x;
    if (idx >= n8) return;
    const float4* s = (const float4*)src + (size_t)idx * 2;
    float4 x = s[0], y = s[1];
    u16x8 o;
    o[0]=f2bf(x.x); o[1]=f2bf(x.y); o[2]=f2bf(x.z); o[3]=f2bf(x.w);
    o[4]=f2bf(y.x); o[5]=f2bf(y.y); o[6]=f2bf(y.z); o[7]=f2bf(y.w);
    *((u16x8*)dst + idx) = o;
}

// ---------------------------------------------------------------------------
// All weights -> transposed bf16 (BT[n][k] = W[k][n]) in one launch.
// ---------------------------------------------------------------------------
__global__ __launch_bounds__(256) void conv_weights(
    const float* __restrict__ W1, const float* __restrict__ W2,
    const float* __restrict__ Wx, const float* __restrict__ Wh,
    const float* __restrict__ eW, const float* __restrict__ sW,
    ushort* __restrict__ W1T, ushort* __restrict__ W2T,
    ushort* __restrict__ WxT, ushort* __restrict__ WhT,
    ushort* __restrict__ eWT, ushort* __restrict__ sWT)
{
    int idx = blockIdx.x * 256 + threadIdx.x;
    if (idx < 16384)       { int n=idx>>7,   k=idx&127;            W1T[idx]=f2bf(W1[k*128+n]); }
    else if (idx < 24576)  { int l=idx-16384;  int n=l>>7,k=l&127; W2T[l]=f2bf(W2[k*64+n]); }
    else if (idx < 90112)  { int l=idx-24576;  int n=l>>7,k=l&127; WxT[l]=f2bf(Wx[k*512+n]); }
    else if (idx < 155648) { int l=idx-90112;  int n=l>>7,k=l&127; WhT[l]=f2bf(Wh[k*512+n]); }
    else if (idx < 163840) { int l=idx-155648; int n=l>>7,k=l&127; eWT[l]=f2bf(eW[k*64+n]); }
    else if (idx < 172032) { int l=idx-163840; int n=l>>7,k=l&127; sWT[l]=f2bf(sW[k*64+n]); }
}

// ---------------------------------------------------------------------------
// bf16 MFMA GEMM: C[M x Nc] = A[M x K] @ BT[Nc x K]^T  (+bias) (+addsrc) (act)
// ---------------------------------------------------------------------------
__global__ __launch_bounds__(256) void gemm_bf16(
    const ushort* __restrict__ A, const ushort* __restrict__ BT,
    float* __restrict__ Cf, ushort* __restrict__ Cb,
    const float* __restrict__ bias, const float* __restrict__ addsrc,
    int M, int K, int Nc, int act)
{
    int w = threadIdx.x >> 6, lane = threadIdx.x & 63;
    int quad = lane >> 4, l16 = lane & 15;
    int m0 = blockIdx.y * 128 + w * 32;
    int n0 = blockIdx.x * 64;
    f32x4 zf = {0.f, 0.f, 0.f, 0.f};
    f32x4 acc[2][4];
    #pragma unroll
    for (int rt = 0; rt < 2; ++rt)
        #pragma unroll
        for (int ct = 0; ct < 4; ++ct) acc[rt][ct] = zf;

    for (int k0 = 0; k0 < K; k0 += 32) {
        int kk = k0 + quad * 8;
        bf16x8 a0 = *(const bf16x8*)(A + (size_t)(m0 + l16) * K + kk);
        bf16x8 a1 = *(const bf16x8*)(A + (size_t)(m0 + 16 + l16) * K + kk);
        bf16x8 b[4];
        #pragma unroll
        for (int ct = 0; ct < 4; ++ct)
            b[ct] = *(const bf16x8*)(BT + (size_t)(n0 + ct * 16 + l16) * K + kk);
        #pragma unroll
        for (int ct = 0; ct < 4; ++ct) {
            acc[0][ct] = __builtin_amdgcn_mfma_f32_16x16x32_bf16(a0, b[ct], acc[0][ct], 0, 0, 0);
            acc[1][ct] = __builtin_amdgcn_mfma_f32_16x16x32_bf16(a1, b[ct], acc[1][ct], 0, 0, 0);
        }
    }

    #pragma unroll
    for (int rt = 0; rt < 2; ++rt) {
        int ibase = m0 + rt * 16 + quad * 4;
        #pragma unroll
        for (int r = 0; r < 4; ++r) {
            int i = ibase + r;
            if (i >= M) continue;
            #pragma unroll
            for (int ct = 0; ct < 4; ++ct) {
                int j = n0 + ct * 16 + l16;
                float v = acc[rt][ct][r];
                if (bias)   v += bias[j];
                if (addsrc) v += addsrc[(size_t)i * Nc + j];
                if (act == 1)      v = fast_tanh(v);
                else if (act == 2) v = fast_sigmoid(v);
                if (Cf) Cf[(size_t)i * Nc + j] = v;
                if (Cb) Cb[(size_t)i * Nc + j] = f2bf(v);
            }
        }
    }
}

// ---------------------------------------------------------------------------
// Per-node attention dots (bf16 h). One wave per row.
// ---------------------------------------------------------------------------
__global__ __launch_bounds__(256) void att_vec128(
    const ushort* __restrict__ h, const float* __restrict__ a_src,
    const float* __restrict__ a_dst, float* __restrict__ as_out,
    float* __restrict__ ad_out, int rows)
{
    int wid  = (blockIdx.x * 256 + threadIdx.x) >> 6;
    int lane = threadIdx.x & 63;
    if (wid >= rows) return;
    const ushort* hr = h + (size_t)wid * 128;
    float v0 = bf2f(hr[lane]), v1 = bf2f(hr[64 + lane]);
    float pa0 = v0 * a_src[lane], pa1 = v1 * a_src[64 + lane];
    float pd0 = v0 * a_dst[lane], pd1 = v1 * a_dst[64 + lane];
    #pragma unroll
    for (int m = 1; m <= 16; m <<= 1) {
        pa0 += __shfl_xor(pa0, m); pa1 += __shfl_xor(pa1, m);
        pd0 += __shfl_xor(pd0, m); pd1 += __shfl_xor(pd1, m);
    }
    if ((lane & 31) == 0) {
        int g = lane >> 5;
        as_out[wid * 4 + g] = pa0; as_out[wid * 4 + 2 + g] = pa1;
        ad_out[wid * 4 + g] = pd0; ad_out[wid * 4 + 2 + g] = pd1;
    }
}

__global__ __launch_bounds__(256) void att_vec64(
    const ushort* __restrict__ h, const float* __restrict__ a_src,
    const float* __restrict__ a_dst, float* __restrict__ as_out,
    float* __restrict__ ad_out, int rows)
{
    int wid  = (blockIdx.x * 256 + threadIdx.x) >> 6;
    int lane = threadIdx.x & 63;
    if (wid >= rows) return;
    float v = bf2f(h[(size_t)wid * 64 + lane]);
    float pa = v * a_src[lane], pd = v * a_dst[lane];
    #pragma unroll
    for (int m = 1; m <= 8; m <<= 1) { pa += __shfl_xor(pa, m); pd += __shfl_xor(pd, m); }
    if ((lane & 15) == 0) {
        int g = lane >> 4;
        as_out[wid * 4 + g] = pa; ad_out[wid * 4 + g] = pd;
    }
}

// ---------------------------------------------------------------------------
// CSR build over dst
// ---------------------------------------------------------------------------
__global__ void count_edges(const int* __restrict__ eidx, int* __restrict__ counts)
{
    int idx = blockIdx.x * 256 + threadIdx.x;
    if (idx >= TE_) return;
    int t = idx / E_, e = idx - t * E_;
    int d = eidx[(size_t)t * 2 * E_ + E_ + e];
    atomicAdd(&counts[t * N_ + d], 1);
}

__global__ __launch_bounds__(1024) void scan_per_t(
    const int* __restrict__ counts, int* __restrict__ rowptr, int* __restrict__ cursor)
{
    const int CH = 10;
    int t = blockIdx.x, i = threadIdx.x;
    int base0 = t * N_;
    int cnt[CH];
    int s = 0;
    int g0 = i * CH;
    #pragma unroll
    for (int q = 0; q < CH; ++q) {
        int g = g0 + q;
        cnt[q] = (g < N_) ? counts[base0 + g] : 0;
        s += cnt[q];
    }
    __shared__ int buf[1024];
    buf[i] = s;
    __syncthreads();
    for (int off = 1; off < 1024; off <<= 1) {
        int v = (i >= off) ? buf[i - off] : 0;
        __syncthreads();
        buf[i] += v;
        __syncthreads();
    }
    int run = t * E_ + buf[i] - s;
    #pragma unroll
    for (int q = 0; q < CH; ++q) {
        int g = g0 + q;
        if (g < N_) {
            rowptr[base0 + g] = run;
            cursor[base0 + g] = run;
            run += cnt[q];
        }
    }
    if (t == T_ - 1 && i == 1023) rowptr[T_ * N_] = TE_;
}

__global__ void fill_csr(const int* __restrict__ eidx, const float* __restrict__ ew,
                         int* __restrict__ cursor, int* __restrict__ src_csr,
                         float* __restrict__ ew_csr)
{
    int idx = blockIdx.x * 256 + threadIdx.x;
    if (idx >= TE_) return;
    int t = idx / E_, e = idx - t * E_;
    int s = eidx[(size_t)t * 2 * E_ + e];
    int d = eidx[(size_t)t * 2 * E_ + E_ + e];
    float w = ew[(size_t)t * E_ + e];
    int pos = atomicAdd(&cursor[t * N_ + d], 1);
    src_csr[pos] = t * N_ + s;
    ew_csr[pos] = w;
}

// ---------------------------------------------------------------------------
// GAT aggregation. Latency analysis (round 2): the edge loop had a serial
// dependent chain src_csr[p] -> as[s]/h[s] (~2 load-latencies PER EDGE, ~32
// edges/node, trivial VALU between) -> latency-bound. v3: chunk-of-4 edges --
// batch the 4 index loads, then issue all as/h loads independently; chain
// depth per 4 edges drops 8 rounds -> 2. as/ad fetched as one float4 + lane
// select (heads live in .x/.y/.z/.w).
// ---------------------------------------------------------------------------
__global__ __launch_bounds__(256) void gat_node_128(
    const ushort* __restrict__ h, const float* __restrict__ as,
    const float* __restrict__ ad, const int* __restrict__ rowptr,
    const int* __restrict__ src_csr, const float* __restrict__ ew_csr,
    ushort* __restrict__ outp, int rows)
{
    int wid  = (blockIdx.x * 256 + threadIdx.x) >> 6;
    int lane = threadIdx.x & 63;
    if (wid >= rows) return;
    int start = rowptr[wid], end = rowptr[wid + 1];
    int h0 = lane >> 5;                       // head pair selector: 0/1
    float ad0 = ad[wid * 4 + h0], ad1 = ad[wid * 4 + 2 + h0];
    float acc0 = 0.f, acc1 = 0.f, den0 = 0.f, den1 = 0.f;

    int p = start;
    for (; p + 4 <= end; p += 4) {
        int s0 = src_csr[p+0], s1 = src_csr[p+1], s2 = src_csr[p+2], s3 = src_csr[p+3];
        float w0 = ew_csr[p+0], w1 = ew_csr[p+1], w2 = ew_csr[p+2], w3 = ew_csr[p+3];
        float4 A0 = *(const float4*)(as + (size_t)s0 * 4);
        float4 A1 = *(const float4*)(as + (size_t)s1 * 4);
        float4 A2 = *(const float4*)(as + (size_t)s2 * 4);
        float4 A3 = *(const float4*)(as + (size_t)s3 * 4);
        const ushort* q0 = h + (size_t)s0 * 128;
        const ushort* q1 = h + (size_t)s1 * 128;
        const ushort* q2 = h + (size_t)s2 * 128;
        const ushort* q3 = h + (size_t)s3 * 128;
        float hx0 = bf2f(q0[lane]), hy0 = bf2f(q0[64 + lane]);
        float hx1 = bf2f(q1[lane]), hy1 = bf2f(q1[64 + lane]);
        float hx2 = bf2f(q2[lane]), hy2 = bf2f(q2[64 + lane]);
        float hx3 = bf2f(q3[lane]), hy3 = bf2f(q3[64 + lane]);
        #define GSTEP(AA, ww, hx, hy) { \
            float e0 = (h0 ? AA.y : AA.x) + ad0; e0 = e0 > 0.f ? e0 : 0.2f * e0; \
            float e1 = (h0 ? AA.w : AA.z) + ad1; e1 = e1 > 0.f ? e1 : 0.2f * e1; \
            float x0 = __expf(e0) * ww, x1 = __expf(e1) * ww; \
            den0 += x0; den1 += x1; acc0 += x0 * hx; acc1 += x1 * hy; }
        GSTEP(A0, w0, hx0, hy0)
        GSTEP(A1, w1, hx1, hy1)
        GSTEP(A2, w2, hx2, hy2)
        GSTEP(A3, w3, hx3, hy3)
    }
    for (; p < end; ++p) {
        int s = src_csr[p];
        float w = ew_csr[p];
        float4 A = *(const float4*)(as + (size_t)s * 4);
        const ushort* q = h + (size_t)s * 128;
        float hx = bf2f(q[lane]), hy = bf2f(q[64 + lane]);
        GSTEP(A, w, hx, hy)
    }
    #undef GSTEP

    float o0 = acc0 / (den0 + 1e-16f);
    float o1 = acc1 / (den1 + 1e-16f);
    o0 = o0 > 0.f ? o0 : (__expf(o0) - 1.f);
    o1 = o1 > 0.f ? o1 : (__expf(o1) - 1.f);
    outp[(size_t)wid * 128 + lane]      = f2bf(o0);
    outp[(size_t)wid * 128 + 64 + lane] = f2bf(o1);
}

__global__ __launch_bounds__(256) void gat_node_64(
    const ushort* __restrict__ h, const float* __restrict__ as,
    const float* __restrict__ ad, const int* __restrict__ rowptr,
    const int* __restrict__ src_csr, const float* __restrict__ ew_csr,
    ushort* __restrict__ outp, int rows)
{
    int wid  = (blockIdx.x * 256 + threadIdx.x) >> 6;
    int lane = threadIdx.x & 63;
    if (wid >= rows) return;
    int start = rowptr[wid], end = rowptr[wid + 1];
    int hh = lane >> 4;                       // head: 0..3
    float adv = ad[wid * 4 + hh];
    float acc = 0.f, den = 0.f;

    int p = start;
    for (; p + 4 <= end; p += 4) {
        int s0 = src_csr[p+0], s1 = src_csr[p+1], s2 = src_csr[p+2], s3 = src_csr[p+3];
        float w0 = ew_csr[p+0], w1 = ew_csr[p+1], w2 = ew_csr[p+2], w3 = ew_csr[p+3];
        float4 A0 = *(const float4*)(as + (size_t)s0 * 4);
        float4 A1 = *(const float4*)(as + (size_t)s1 * 4);
        float4 A2 = *(const float4*)(as + (size_t)s2 * 4);
        float4 A3 = *(const float4*)(as + (size_t)s3 * 4);
        float hv0 = bf2f(h[(size_t)s0 * 64 + lane]);
        float hv1 = bf2f(h[(size_t)s1 * 64 + lane]);
        float hv2 = bf2f(h[(size_t)s2 * 64 + lane]);
        float hv3 = bf2f(h[(size_t)s3 * 64 + lane]);
        #define GSTEP64(AA, ww, hv) { \
            float e = (hh & 2 ? (hh & 1 ? AA.w : AA.z) : (hh & 1 ? AA.y : AA.x)) + adv; \
            e = e > 0.f ? e : 0.2f * e; \
            float x = __expf(e) * ww; \
            den += x; acc += x * hv; }
        GSTEP64(A0, w0, hv0)
        GSTEP64(A1, w1, hv1)
        GSTEP64(A2, w2, hv2)
        GSTEP64(A3, w3, hv3)
    }
    for (; p < end; ++p) {
        int s = src_csr[p];
        float w = ew_csr[p];
        float4 A = *(const float4*)(as + (size_t)s * 4);
        float hv = bf2f(h[(size_t)s * 64 + lane]);
        GSTEP64(A, w, hv)
    }
    #undef GSTEP64

    float o = acc / (den + 1e-16f);
    o = o > 0.f ? o : (__expf(o) - 1.f);
    outp[(size_t)wid * 64 + lane] = f2bf(o);
}

// ---------------------------------------------------------------------------
// Meso pooling + agg assembly (g2 in bf16, agg out bf16)
// ---------------------------------------------------------------------------
__global__ __launch_bounds__(256) void meso_acc(
    const ushort* __restrict__ g2, const int* __restrict__ part,
    const float* __restrict__ Dw, float* __restrict__ msum, float* __restrict__ mden)
{
    int wid  = (blockIdx.x * 256 + threadIdx.x) >> 6;
    int lane = threadIdx.x & 63;
    if (wid >= TN_) return;
    int t = wid / N_;
    int p = part[wid];
    float dv = Dw[wid];
    atomicAdd(&msum[((size_t)(t * NC_ + p) << 6) + lane], dv * bf2f(g2[(size_t)wid * 64 + lane]));
    if (lane == 0) atomicAdd(&mden[t * NC_ + p], dv);
}

__global__ void agg_assemble(
    const ushort* __restrict__ g2, const int* __restrict__ part,
    const float* __restrict__ msum, const float* __restrict__ mden,
    ushort* __restrict__ agg)
{
    int idx = blockIdx.x * 256 + threadIdx.x;   // < TN*128
    int row = idx >> 7, d = idx & 127;
    ushort v;
    if (d < 64) {
        v = g2[(size_t)row * 64 + d];
    } else {
        int t = row / N_;
        int p = part[row];
        v = f2bf(msum[((size_t)(t * NC_ + p) << 6) + (d - 64)] / (mden[t * NC_ + p] + 1e-16f));
    }
    agg[idx] = v;
}

// ---------------------------------------------------------------------------
// Fused LSTM step: z = h@Wh + zx (zx = x@Wx + b, precomputed); gates from LDS;
// c,h updated in place. Block = 512 thr (8 waves), 32 rows x 512 cols; wave w
// owns cols w*64..w*64+63 (2x4 mfma tiles). LDS z-tile [32][516] (stride 516:
// 2-way-max bank aliasing = free). In-place h is safe: a block writes only
// the 32 h-rows it alone reads, after the post-MFMA barrier.
// Replaces gemm(zbuf) + lstm_cell: kills the 20 MB zbuf round-trip per step
// and halves the serial dispatch count.
// ---------------------------------------------------------------------------
__global__ __launch_bounds__(512) void lstm_fused(
    const ushort* __restrict__ hin, const ushort* __restrict__ WhT,
    const float* __restrict__ zx, float* __restrict__ c,
    ushort* __restrict__ hout)
{
    __shared__ float zt[32][516];
    int w = threadIdx.x >> 6, lane = threadIdx.x & 63;
    int quad = lane >> 4, l16 = lane & 15;
    int m0 = blockIdx.x * 32;
    int n0 = w * 64;

    f32x4 zf = {0.f, 0.f, 0.f, 0.f};
    f32x4 acc[2][4];
    #pragma unroll
    for (int rt = 0; rt < 2; ++rt)
        #pragma unroll
        for (int ct = 0; ct < 4; ++ct) acc[rt][ct] = zf;

    #pragma unroll
    for (int k0 = 0; k0 < 128; k0 += 32) {
        int kk = k0 + quad * 8;
        bf16x8 a0 = *(const bf16x8*)(hin + (size_t)(m0 + l16) * 128 + kk);
        bf16x8 a1 = *(const bf16x8*)(hin + (size_t)(m0 + 16 + l16) * 128 + kk);
        bf16x8 b[4];
        #pragma unroll
        for (int ct = 0; ct < 4; ++ct)
            b[ct] = *(const bf16x8*)(WhT + (size_t)(n0 + ct * 16 + l16) * 128 + kk);
        #pragma unroll
        for (int ct = 0; ct < 4; ++ct) {
            acc[0][ct] = __builtin_amdgcn_mfma_f32_16x16x32_bf16(a0, b[ct], acc[0][ct], 0, 0, 0);
            acc[1][ct] = __builtin_amdgcn_mfma_f32_16x16x32_bf16(a1, b[ct], acc[1][ct], 0, 0, 0);
        }
    }

    // z = acc + zx  -> LDS stage (rows >= N_ stage garbage; cell is guarded)
    #pragma unroll
    for (int rt = 0; rt < 2; ++rt) {
        #pragma unroll
        for (int r = 0; r < 4; ++r) {
            int li = rt * 16 + quad * 4 + r;
            size_t gi = (size_t)(m0 + li);
            #pragma unroll
            for (int ct = 0; ct < 4; ++ct) {
                int j = n0 + ct * 16 + l16;
                zt[li][j] = acc[rt][ct][r] + zx[gi * 512 + j];
            }
        }
    }
    __syncthreads();

    // cell: thread -> (row r, cols j0..j0+7)
    int r  = threadIdx.x >> 4;
    int j0 = (threadIdx.x & 15) * 8;
    int gi = m0 + r;
    if (gi < N_) {
        f32x4 vi[2], vf[2], vg[2], vo[2], vc[2];
        #pragma unroll
        for (int hb = 0; hb < 2; ++hb) {
            int jj = j0 + hb * 4;
            vi[hb] = *(const f32x4*)&zt[r][jj];
            vf[hb] = *(const f32x4*)&zt[r][128 + jj];
            vg[hb] = *(const f32x4*)&zt[r][256 + jj];
            vo[hb] = *(const f32x4*)&zt[r][384 + jj];
            vc[hb] = *(const f32x4*)(c + (size_t)gi * 128 + jj);
        }
        u16x8 ho;
        #pragma unroll
        for (int e = 0; e < 8; ++e) {
            int hb = e >> 2, q = e & 3;
            float si = fast_sigmoid(vi[hb][q]);
            float sf = fast_sigmoid(vf[hb][q]);
            float so = fast_sigmoid(vo[hb][q]);
            float cn = sf * vc[hb][q] + si * fast_tanh(vg[hb][q]);
            vc[hb][q] = cn;
            ho[e] = f2bf(so * fast_tanh(cn));
        }
        *(f32x4*)(c + (size_t)gi * 128 + j0)     = vc[0];
        *(f32x4*)(c + (size_t)gi * 128 + j0 + 4) = vc[1];
        *(u16x8*)(hout + (size_t)gi * 128 + j0)  = ho;
    }
}

// ---------------------------------------------------------------------------
// Column sum-of-squares for emb (fp32), then normalize -> bf16 + per-row sq
// ---------------------------------------------------------------------------
__global__ __launch_bounds__(256) void col_sumsq(const float* __restrict__ emb,
                                                 float* __restrict__ colss)
{
    int tid = threadIdx.x;
    int col = tid & 63, rq = tid >> 6;
    float s = 0.f;
    for (int r = blockIdx.x * 4 + rq; r < N_; r += 40 * 4) {
        float v = emb[(size_t)r * 64 + col];
        s += v * v;
    }
    __shared__ float red[256];
    red[tid] = s;
    __syncthreads();
    if (tid < 64)
        atomicAdd(&colss[tid], red[tid] + red[tid + 64] + red[tid + 128] + red[tid + 192]);
}

// sq computed from the bf16-ROUNDED values so the i==j cancellation in the
// final dist is exact.
__global__ __launch_bounds__(256) void norm_rows(const float* __restrict__ emb,
                                                 const float* __restrict__ colss,
                                                 ushort* __restrict__ embb,
                                                 float* __restrict__ sq, int rows)
{
    int wid  = (blockIdx.x * 256 + threadIdx.x) >> 6;
    int lane = threadIdx.x & 63;
    if (wid >= rows) return;
    float nv = emb[(size_t)wid * 64 + lane] / sqrtf(colss[lane]);
    ushort ub = f2bf(nv);
    embb[(size_t)wid * 64 + lane] = ub;
    float nq = bf2f(ub);
    float q = nq * nq;
    #pragma unroll
    for (int m = 1; m <= 32; m <<= 1) q += __shfl_xor(q, m);
    if (lane == 0) sq[wid] = q;
}

// ---------------------------------------------------------------------------
// Fused final, MFMA: S = scal.scal^T, G = emb.emb^T (K=64, bf16),
// out = 1 + tanh((2G - sq_i - sq_j) * S).
// Full-line NT store scheme (see round-2 notes): 128-row band x 640 cols per
// block; per 128-col tile, epilogue -> LDS -> copy-out with odd rows shifted
// -64 B so every dwordx4x32-lane store covers exactly 4 full 128 B lines
// (row stride 40000 B = 64 mod 128). Edge strip double-buffered in LDS.
// ---------------------------------------------------------------------------
#define FTJ_   5
#define FCOLS_ (FTJ_*128)

__global__ __launch_bounds__(256) void final_adj_mfma(
    const ushort* __restrict__ embb, const ushort* __restrict__ scalb,
    const float* __restrict__ sq, float* __restrict__ outp)
{
    __shared__ float cur[128][132];      // 128x128 tile, +4 pad: conflict-free b128
    __shared__ float edg[2][64][16];     // odd local rows' cols [112,128) of tile t

    int w = threadIdx.x >> 6, lane = threadIdx.x & 63;
    int quad = lane >> 4, l16 = lane & 15;
    int bi = blockIdx.y * 128;
    int Wb = blockIdx.x * FCOLS_;
    int wi = bi + (w >> 1) * 64;         // wave row base (global)

    float sqi[4];
    #pragma unroll
    for (int rt = 0; rt < 4; ++rt) sqi[rt] = sq[wi + rt * 16 + l16];

    int tLast = (N_ - 1 - Wb) / 128;
    if (tLast > FTJ_ - 1) tLast = FTJ_ - 1;

    for (int t = 0; t <= tLast; ++t) {
        int Wt = Wb + t * 128;
        int wj = Wt + (w & 1) * 64;      // wave col base (global)

        f32x4 zf = {0.f, 0.f, 0.f, 0.f};
        f32x4 accG[4][4], accS[4][4];
        #pragma unroll
        for (int rt = 0; rt < 4; ++rt)
            #pragma unroll
            for (int ct = 0; ct < 4; ++ct) { accG[rt][ct] = zf; accS[rt][ct] = zf; }

        #pragma unroll
        for (int ks = 0; ks < 2; ++ks) {
            int k0 = ks * 32 + quad * 8;
            bf16x8 ae[4], af[4], be[4], bs[4];
            #pragma unroll
            for (int q = 0; q < 4; ++q) {
                int ri = wi + q * 16 + l16;
                int rj = wj + q * 16 + l16;          // max 10111 < NPAD_
                ae[q] = *(const bf16x8*)(embb  + (size_t)ri * 64 + k0);
                af[q] = *(const bf16x8*)(scalb + (size_t)ri * 64 + k0);
                be[q] = *(const bf16x8*)(embb  + (size_t)rj * 64 + k0);
                bs[q] = *(const bf16x8*)(scalb + (size_t)rj * 64 + k0);
            }
            // Swapped operands (G,S symmetric): i = wave_row + rt*16 + l16,
            // j = wave_col + ct*16 + quad*4 + r  (bitwise-identical values).
            #pragma unroll
            for (int rt = 0; rt < 4; ++rt)
                #pragma unroll
                for (int ct = 0; ct < 4; ++ct) {
                    accG[rt][ct] = __builtin_amdgcn_mfma_f32_16x16x32_bf16(be[ct], ae[rt], accG[rt][ct], 0, 0, 0);
                    accS[rt][ct] = __builtin_amdgcn_mfma_f32_16x16x32_bf16(bs[ct], af[rt], accS[rt][ct], 0, 0, 0);
                }
        }

        __syncthreads();   // previous copy-out finished reading cur/edg

        #pragma unroll
        for (int rt = 0; rt < 4; ++rt) {
            int li = (w >> 1) * 64 + rt * 16 + l16;
            float si = sqi[rt];
            #pragma unroll
            for (int ct = 0; ct < 4; ++ct) {
                int lj = (w & 1) * 64 + ct * 16 + quad * 4;
                const float4 sj = *(const float4*)(sq + Wt + lj);
                float sjr[4] = { sj.x, sj.y, sj.z, sj.w };
                f32x4 v;
                #pragma unroll
                for (int r = 0; r < 4; ++r) {
                    float G = accG[rt][ct][r], S = accS[rt][ct][r];
                    float dist = 2.f * G - si - sjr[r];
                    float e = __expf(2.f * dist * S);
                    v[r] = 2.f - 2.f / (e + 1.f);
                }
                *(f32x4*)&cur[li][lj] = v;
                if ((w & 1) && ct == 3 && (li & 1))
                    *(f32x4*)&edg[t & 1][li >> 1][quad * 4] = v;
            }
        }

        __syncthreads();

        int lane5 = lane & 31;
        #pragma unroll
        for (int pass = 0; pass < 16; ++pass) {
            int r = pass * 8 + (lane >> 5) * 4 + w;
            int i = bi + r;
            if (i < N_) {
                if (!(r & 1)) {
                    int gcol = Wt + lane5 * 4;
                    if (gcol < N_)
                        __builtin_nontemporal_store(*(const f32x4*)&cur[r][lane5 * 4],
                            (f32x4*)(outp + (size_t)i * N_ + gcol));
                } else {
                    int gcol = Wt - 16 + lane5 * 4;
                    if ((t > 0 || lane5 >= 4) && gcol >= 0 && gcol < N_) {
                        f32x4 v;
                        if (lane5 < 4) v = *(const f32x4*)&edg[(t & 1) ^ 1][r >> 1][lane5 * 4];
                        else           v = *(const f32x4*)&cur[r][lane5 * 4 - 16];
                        __builtin_nontemporal_store(v,
                            (f32x4*)(outp + (size_t)i * N_ + gcol));
                    }
                }
            }
        }
    }

    // flush: trailing 16 cols of the band's last tile, odd rows (cur intact)
    {
        int tid = threadIdx.x;
        int r = ((tid >> 2) << 1) | 1;            // odd rows 1..127
        int k = (tid & 3) * 4;
        int i = bi + r;
        int gcol = Wb + tLast * 128 + 112 + k;
        if (i < N_ && gcol < N_) {
            f32x4 v = *(const f32x4*)&cur[r][112 + k];
            __builtin_nontemporal_store(v, (f32x4*)(outp + (size_t)i * N_ + gcol));
        }
    }
}

// ---------------------------------------------------------------------------
extern "C" void kernel_launch(void* const* d_in, const int* in_sizes, int n_in,
                              void* d_out, int out_size, void* d_ws, size_t ws_size,
                              hipStream_t stream)
{
    (void)in_sizes; (void)n_in; (void)out_size; (void)ws_size;
    const float* feat    = (const float*)d_in[0];
    const float* eweight = (const float*)d_in[1];
    const float* Dw      = (const float*)d_in[2];
    const float* W1      = (const float*)d_in[3];
    const float* a_src1  = (const float*)d_in[4];
    const float* a_dst1  = (const float*)d_in[5];
    const float* W2      = (const float*)d_in[6];
    const float* a_src2  = (const float*)d_in[7];
    const float* a_dst2  = (const float*)d_in[8];
    const float* Wx      = (const float*)d_in[9];
    const float* Wh      = (const float*)d_in[10];
    const float* b_lstm  = (const float*)d_in[11];
    const float* emb_W   = (const float*)d_in[12];
    const float* emb_b   = (const float*)d_in[13];
    const float* scal_W  = (const float*)d_in[14];
    const float* scal_b  = (const float*)d_in[15];
    const int*   eidx    = (const int*)d_in[16];
    const int*   part    = (const int*)d_in[17];

    // ---- scratch layout (floats) inside d_out (dead before final_adj) ----
    float* out = (float*)d_out;
    ushort* h1b   = (ushort*)(out + 0);          // 80000x128 bf16 (5,120,000 f)
    ushort* g1b   = (ushort*)(out + 5120000);    // 80000x128 bf16
    ushort* h2b   = (ushort*)(out + 10240000);   // 80000x64 bf16
    ushort* g2b   = (ushort*)(out + 12800000);   // 80000x64 bf16
    float* as1    = out + 15360000;              // TN*4
    float* ad1    = out + 15680000;
    float* as2    = out + 16000000;
    float* ad2    = out + 16320000;
    int*   rowptr = (int*)(out + 16640000);      // TN+1
    int*   cursor = (int*)(out + 16720064);
    int*   counts = (int*)(out + 16800064);
    int*   src_csr= (int*)(out + 16880064);      // TE
    float* ew_csr = out + 19440064;              // TE
    float* msum   = out + 22000064;              // T*100*64
    float* mden   = out + 22051264;              // T*100
    ushort* aggb  = (ushort*)(out + 22052064);   // 80000x128 bf16
    float* ZX     = out + 27172064;              // 80000x512 fp32
    // (old zbuf region 68132064.. now unused)
    float* cstate = out + 73252064;              // 10000x128 fp32
    ushort* hbf   = (ushort*)(out + 74532064);   // NPAD x128 bf16 (647,168 f)
    ushort* featb = (ushort*)(out + 75179232);   // 80000x128 bf16
    ushort* W1T   = (ushort*)(out + 80299232);   // 128x128
    ushort* W2T   = (ushort*)(out + 80307424);   // 64x128
    ushort* WxT   = (ushort*)(out + 80311520);   // 512x128
    ushort* WhT   = (ushort*)(out + 80344288);   // 512x128
    ushort* eWT   = (ushort*)(out + 80377056);   // 64x128
    ushort* sWT   = (ushort*)(out + 80381152);   // 64x128
    float* embf   = out + 80385248;              // 10000x64 fp32
    float* colss  = out + 81025248;              // 64

    // ---- live-at-final buffers in d_ws ----
    ushort* embb  = (ushort*)d_ws;               // NPAD x 64 bf16
    ushort* scalb = embb + (size_t)NPAD_ * 64;   // NPAD x 64 bf16
    float*  sq    = (float*)(scalb + (size_t)NPAD_ * 64);  // NPAD fp32

    // ---- zero-init accumulation targets ----
    hipMemsetAsync(counts, 0, TN_ * sizeof(int), stream);
    hipMemsetAsync(msum, 0, (T_ * NC_ * 64 + T_ * NC_) * sizeof(float), stream);
    hipMemsetAsync(cstate, 0, (size_t)N_ * DR_ * sizeof(float), stream);
    hipMemsetAsync(hbf, 0, (size_t)NPAD_ * DR_ * sizeof(ushort), stream);  // h0 = 0 (+pad)
    hipMemsetAsync(colss, 0, 64 * sizeof(float), stream);

    // ---- converts ----
    conv_feat<<<5000, 256, 0, stream>>>(feat, featb, TN_ * F_ / 8);
    conv_weights<<<672, 256, 0, stream>>>(W1, W2, Wx, Wh, emb_W, scal_W,
                                          W1T, W2T, WxT, WhT, eWT, sWT);

    // ---- GAT layer 1 (batched over T) ----
    gemm_bf16<<<dim3(2, 625), 256, 0, stream>>>(featb, W1T, nullptr, h1b, nullptr, nullptr, TN_, 128, 128, 0);
    att_vec128<<<TN_/4, 256, 0, stream>>>(h1b, a_src1, a_dst1, as1, ad1, TN_);
    count_edges<<<(TE_+255)/256, 256, 0, stream>>>(eidx, counts);
    scan_per_t<<<T_, 1024, 0, stream>>>(counts, rowptr, cursor);
    fill_csr<<<(TE_+255)/256, 256, 0, stream>>>(eidx, eweight, cursor, src_csr, ew_csr);
    gat_node_128<<<TN_/4, 256, 0, stream>>>(h1b, as1, ad1, rowptr, src_csr, ew_csr, g1b, TN_);

    // ---- GAT layer 2 ----
    gemm_bf16<<<dim3(1, 625), 256, 0, stream>>>(g1b, W2T, nullptr, h2b, nullptr, nullptr, TN_, 128, 64, 0);
    att_vec64<<<TN_/4, 256, 0, stream>>>(h2b, a_src2, a_dst2, as2, ad2, TN_);
    gat_node_64<<<TN_/4, 256, 0, stream>>>(h2b, as2, ad2, rowptr, src_csr, ew_csr, g2b, TN_);

    // ---- meso + agg ----
    meso_acc<<<TN_/4, 256, 0, stream>>>(g2b, part, Dw, msum, mden);
    agg_assemble<<<TN_*128/256, 256, 0, stream>>>(g2b, part, msum, mden, aggb);

    // ---- LSTM: batched input projection, then 8 fused recurrent steps ----
    gemm_bf16<<<dim3(8, 625), 256, 0, stream>>>(aggb, WxT, ZX, nullptr, b_lstm, nullptr, TN_, 128, 512, 0);
    for (int t = 0; t < T_; ++t)
        lstm_fused<<<(N_ + 31) / 32, 512, 0, stream>>>(hbf, WhT, ZX + (size_t)t * N_ * 512,
                                                       cstate, hbf);

    // ---- decoder heads ----
    gemm_bf16<<<dim3(1, 79), 256, 0, stream>>>(hbf, eWT, embf, nullptr, emb_b, nullptr, N_, 128, 64, 1);
    gemm_bf16<<<dim3(1, 79), 256, 0, stream>>>(hbf, sWT, nullptr, scalb, scal_b, nullptr, N_, 128, 64, 2);
    col_sumsq<<<40, 256, 0, stream>>>(embf, colss);
    norm_rows<<<(N_+3)/4, 256, 0, stream>>>(embf, colss, embb, sq, N_);

    // ---- fused final ----
    final_adj_mfma<<<dim3(16, 79), 256, 0, stream>>>(embb, scalb, sq, out);
}

// Round 4
// 1608.157 us; speedup vs baseline: 1.2996x; 1.0195x over previous
//
#include <hip/hip_runtime.h>
#include <cstddef>
#include <cstdint>

// Problem constants (fixed by setup_inputs)
#define T_   8
#define N_   10000
#define E_   320000
#define F_   128
#define D1_  128
#define D2_  64
#define DR_  128
#define NC_  100
#define TN_  (T_*N_)
#define TE_  (T_*E_)
#define NPAD_ 10112   // 79*128, row padding for M=10000 MFMA tiles

typedef __attribute__((ext_vector_type(8))) short bf16x8;
typedef __attribute__((ext_vector_type(8))) ushort u16x8;
typedef __attribute__((ext_vector_type(4))) float f32x4;

__device__ __forceinline__ float bf2f(ushort u) {
    return __uint_as_float(((unsigned int)u) << 16);
}
__device__ __forceinline__ ushort f2bf(float f) {
    unsigned int u = __float_as_uint(f);
    unsigned int r = (u + 0x7FFFu + ((u >> 16) & 1u)) >> 16;   // RNE
    return (ushort)r;
}
// numerically safe fast tanh / sigmoid (inf-safe forms)
__device__ __forceinline__ float fast_tanh(float x) {
    float t = __expf(2.f * x);
    return 1.f - 2.f / (t + 1.f);
}
__device__ __forceinline__ float fast_sigmoid(float x) {
    return 1.f / (1.f + __expf(-x));
}

// ---------------------------------------------------------------------------
// fp32 -> bf16 bulk convert (feat). 8 elems/thread.
// ---------------------------------------------------------------------------
__global__ __launch_bounds__(256) void conv_feat(const float* __restrict__ src,
                                                 ushort* __restrict__ dst, int n8)
{
    int idx = blockIdx.x * 256 + threadIdx.x;
    if (idx >= n8) return;
    const float4* s = (const float4*)src + (size_t)idx * 2;
    float4 x = s[0], y = s[1];
    u16x8 o;
    o[0]=f2bf(x.x); o[1]=f2bf(x.y); o[2]=f2bf(x.z); o[3]=f2bf(x.w);
    o[4]=f2bf(y.x); o[5]=f2bf(y.y); o[6]=f2bf(y.z); o[7]=f2bf(y.w);
    *((u16x8*)dst + idx) = o;
}

// ---------------------------------------------------------------------------
// All weights -> transposed bf16 (BT[n][k] = W[k][n]) in one launch.
// ---------------------------------------------------------------------------
__global__ __launch_bounds__(256) void conv_weights(
    const float* __restrict__ W1, const float* __restrict__ W2,
    const float* __restrict__ Wx, const float* __restrict__ Wh,
    const float* __restrict__ eW, const float* __restrict__ sW,
    ushort* __restrict__ W1T, ushort* __restrict__ W2T,
    ushort* __restrict__ WxT, ushort* __restrict__ WhT,
    ushort* __restrict__ eWT, ushort* __restrict__ sWT)
{
    int idx = blockIdx.x * 256 + threadIdx.x;
    if (idx < 16384)       { int n=idx>>7,   k=idx&127;            W1T[idx]=f2bf(W1[k*128+n]); }
    else if (idx < 24576)  { int l=idx-16384;  int n=l>>7,k=l&127; W2T[l]=f2bf(W2[k*64+n]); }
    else if (idx < 90112)  { int l=idx-24576;  int n=l>>7,k=l&127; WxT[l]=f2bf(Wx[k*512+n]); }
    else if (idx < 155648) { int l=idx-90112;  int n=l>>7,k=l&127; WhT[l]=f2bf(Wh[k*512+n]); }
    else if (idx < 163840) { int l=idx-155648; int n=l>>7,k=l&127; eWT[l]=f2bf(eW[k*64+n]); }
    else if (idx < 172032) { int l=idx-163840; int n=l>>7,k=l&127; sWT[l]=f2bf(sW[k*64+n]); }
}

// ---------------------------------------------------------------------------
// bf16 MFMA GEMM: C[M x Nc] = A[M x K] @ BT[Nc x K]^T  (+bias) (+addsrc) (act)
// ---------------------------------------------------------------------------
__global__ __launch_bounds__(256) void gemm_bf16(
    const ushort* __restrict__ A, const ushort* __restrict__ BT,
    float* __restrict__ Cf, ushort* __restrict__ Cb,
    const float* __restrict__ bias, const float* __restrict__ addsrc,
    int M, int K, int Nc, int act)
{
    int w = threadIdx.x >> 6, lane = threadIdx.x & 63;
    int quad = lane >> 4, l16 = lane & 15;
    int m0 = blockIdx.y * 128 + w * 32;
    int n0 = blockIdx.x * 64;
    f32x4 zf = {0.f, 0.f, 0.f, 0.f};
    f32x4 acc[2][4];
    #pragma unroll
    for (int rt = 0; rt < 2; ++rt)
        #pragma unroll
        for (int ct = 0; ct < 4; ++ct) acc[rt][ct] = zf;

    for (int k0 = 0; k0 < K; k0 += 32) {
        int kk = k0 + quad * 8;
        bf16x8 a0 = *(const bf16x8*)(A + (size_t)(m0 + l16) * K + kk);
        bf16x8 a1 = *(const bf16x8*)(A + (size_t)(m0 + 16 + l16) * K + kk);
        bf16x8 b[4];
        #pragma unroll
        for (int ct = 0; ct < 4; ++ct)
            b[ct] = *(const bf16x8*)(BT + (size_t)(n0 + ct * 16 + l16) * K + kk);
        #pragma unroll
        for (int ct = 0; ct < 4; ++ct) {
            acc[0][ct] = __builtin_amdgcn_mfma_f32_16x16x32_bf16(a0, b[ct], acc[0][ct], 0, 0, 0);
            acc[1][ct] = __builtin_amdgcn_mfma_f32_16x16x32_bf16(a1, b[ct], acc[1][ct], 0, 0, 0);
        }
    }

    #pragma unroll
    for (int rt = 0; rt < 2; ++rt) {
        int ibase = m0 + rt * 16 + quad * 4;
        #pragma unroll
        for (int r = 0; r < 4; ++r) {
            int i = ibase + r;
            if (i >= M) continue;
            #pragma unroll
            for (int ct = 0; ct < 4; ++ct) {
                int j = n0 + ct * 16 + l16;
                float v = acc[rt][ct][r];
                if (bias)   v += bias[j];
                if (addsrc) v += addsrc[(size_t)i * Nc + j];
                if (act == 1)      v = fast_tanh(v);
                else if (act == 2) v = fast_sigmoid(v);
                if (Cf) Cf[(size_t)i * Nc + j] = v;
                if (Cb) Cb[(size_t)i * Nc + j] = f2bf(v);
            }
        }
    }
}

// ---------------------------------------------------------------------------
// Per-node attention dots (bf16 h). One wave per row.
// ---------------------------------------------------------------------------
__global__ __launch_bounds__(256) void att_vec128(
    const ushort* __restrict__ h, const float* __restrict__ a_src,
    const float* __restrict__ a_dst, float* __restrict__ as_out,
    float* __restrict__ ad_out, int rows)
{
    int wid  = (blockIdx.x * 256 + threadIdx.x) >> 6;
    int lane = threadIdx.x & 63;
    if (wid >= rows) return;
    const ushort* hr = h + (size_t)wid * 128;
    float v0 = bf2f(hr[lane]), v1 = bf2f(hr[64 + lane]);
    float pa0 = v0 * a_src[lane], pa1 = v1 * a_src[64 + lane];
    float pd0 = v0 * a_dst[lane], pd1 = v1 * a_dst[64 + lane];
    #pragma unroll
    for (int m = 1; m <= 16; m <<= 1) {
        pa0 += __shfl_xor(pa0, m); pa1 += __shfl_xor(pa1, m);
        pd0 += __shfl_xor(pd0, m); pd1 += __shfl_xor(pd1, m);
    }
    if ((lane & 31) == 0) {
        int g = lane >> 5;
        as_out[wid * 4 + g] = pa0; as_out[wid * 4 + 2 + g] = pa1;
        ad_out[wid * 4 + g] = pd0; ad_out[wid * 4 + 2 + g] = pd1;
    }
}

__global__ __launch_bounds__(256) void att_vec64(
    const ushort* __restrict__ h, const float* __restrict__ a_src,
    const float* __restrict__ a_dst, float* __restrict__ as_out,
    float* __restrict__ ad_out, int rows)
{
    int wid  = (blockIdx.x * 256 + threadIdx.x) >> 6;
    int lane = threadIdx.x & 63;
    if (wid >= rows) return;
    float v = bf2f(h[(size_t)wid * 64 + lane]);
    float pa = v * a_src[lane], pd = v * a_dst[lane];
    #pragma unroll
    for (int m = 1; m <= 8; m <<= 1) { pa += __shfl_xor(pa, m); pd += __shfl_xor(pd, m); }
    if ((lane & 15) == 0) {
        int g = lane >> 4;
        as_out[wid * 4 + g] = pa; ad_out[wid * 4 + g] = pd;
    }
}

// ---------------------------------------------------------------------------
// CSR build over dst. Edge payload stored as ONE int2 {src_gid, bits(ew)} so
// the scatter is a single 8 B store and the gather side can read 2 edges per
// int4 load.
// ---------------------------------------------------------------------------
__global__ void count_edges(const int* __restrict__ eidx, int* __restrict__ counts)
{
    int idx = blockIdx.x * 256 + threadIdx.x;
    if (idx >= TE_) return;
    int t = idx / E_, e = idx - t * E_;
    int d = eidx[(size_t)t * 2 * E_ + E_ + e];
    atomicAdd(&counts[t * N_ + d], 1);
}

__global__ __launch_bounds__(1024) void scan_per_t(
    const int* __restrict__ counts, int* __restrict__ rowptr, int* __restrict__ cursor)
{
    const int CH = 10;
    int t = blockIdx.x, i = threadIdx.x;
    int base0 = t * N_;
    int cnt[CH];
    int s = 0;
    int g0 = i * CH;
    #pragma unroll
    for (int q = 0; q < CH; ++q) {
        int g = g0 + q;
        cnt[q] = (g < N_) ? counts[base0 + g] : 0;
        s += cnt[q];
    }
    __shared__ int buf[1024];
    buf[i] = s;
    __syncthreads();
    for (int off = 1; off < 1024; off <<= 1) {
        int v = (i >= off) ? buf[i - off] : 0;
        __syncthreads();
        buf[i] += v;
        __syncthreads();
    }
    int run = t * E_ + buf[i] - s;
    #pragma unroll
    for (int q = 0; q < CH; ++q) {
        int g = g0 + q;
        if (g < N_) {
            rowptr[base0 + g] = run;
            cursor[base0 + g] = run;
            run += cnt[q];
        }
    }
    if (t == T_ - 1 && i == 1023) rowptr[T_ * N_] = TE_;
}

__global__ void fill_csr(const int* __restrict__ eidx, const float* __restrict__ ew,
                         int* __restrict__ cursor, int2* __restrict__ csr)
{
    int idx = blockIdx.x * 256 + threadIdx.x;
    if (idx >= TE_) return;
    int t = idx / E_, e = idx - t * E_;
    int s = eidx[(size_t)t * 2 * E_ + e];
    int d = eidx[(size_t)t * 2 * E_ + E_ + e];
    float w = ew[(size_t)t * E_ + e];
    int pos = atomicAdd(&cursor[t * N_ + d], 1);
    csr[pos] = make_int2(t * N_ + s, __float_as_int(w));
}

// ---------------------------------------------------------------------------
// GAT aggregation. Latency-bound gather: chunk-of-8 edges, all loads of a
// chunk issued independently (8 h-rows + 8 as-float4 + 4 int4 edge loads in
// flight), dependent-chain rounds per 8 edges = 2.
// ---------------------------------------------------------------------------
__global__ __launch_bounds__(256) void gat_node_128(
    const ushort* __restrict__ h, const float* __restrict__ as,
    const float* __restrict__ ad, const int* __restrict__ rowptr,
    const int2* __restrict__ csr, ushort* __restrict__ outp, int rows)
{
    int wid  = (blockIdx.x * 256 + threadIdx.x) >> 6;
    int lane = threadIdx.x & 63;
    if (wid >= rows) return;
    int start = rowptr[wid], end = rowptr[wid + 1];
    int h0 = lane >> 5;                       // head pair selector: 0/1
    float ad0 = ad[wid * 4 + h0], ad1 = ad[wid * 4 + 2 + h0];
    float acc0 = 0.f, acc1 = 0.f, den0 = 0.f, den1 = 0.f;

    #define GSTEP(AA, ww, hx, hy) { \
        float e0 = (h0 ? AA.y : AA.x) + ad0; e0 = e0 > 0.f ? e0 : 0.2f * e0; \
        float e1 = (h0 ? AA.w : AA.z) + ad1; e1 = e1 > 0.f ? e1 : 0.2f * e1; \
        float x0 = __expf(e0) * ww, x1 = __expf(e1) * ww; \
        den0 += x0; den1 += x1; acc0 += x0 * hx; acc1 += x1 * hy; }

    int p = start;
    if ((p & 1) && p < end) {                 // align to int4 (2-edge) boundary
        int2 E = csr[p];
        float4 A = *(const float4*)(as + (size_t)E.x * 4);
        const ushort* q = h + (size_t)E.x * 128;
        float hx = bf2f(q[lane]), hy = bf2f(q[64 + lane]);
        float w = __int_as_float(E.y);
        GSTEP(A, w, hx, hy)
        ++p;
    }
    for (; p + 8 <= end; p += 8) {
        int4 e0 = *(const int4*)(csr + p);
        int4 e1 = *(const int4*)(csr + p + 2);
        int4 e2 = *(const int4*)(csr + p + 4);
        int4 e3 = *(const int4*)(csr + p + 6);
        int ss[8] = { e0.x, e0.z, e1.x, e1.z, e2.x, e2.z, e3.x, e3.z };
        float wwv[8] = { __int_as_float(e0.y), __int_as_float(e0.w),
                         __int_as_float(e1.y), __int_as_float(e1.w),
                         __int_as_float(e2.y), __int_as_float(e2.w),
                         __int_as_float(e3.y), __int_as_float(e3.w) };
        float4 Av[8];
        #pragma unroll
        for (int q = 0; q < 8; ++q) Av[q] = *(const float4*)(as + (size_t)ss[q] * 4);
        float hx[8], hy[8];
        #pragma unroll
        for (int q = 0; q < 8; ++q) {
            const ushort* hp = h + (size_t)ss[q] * 128;
            hx[q] = bf2f(hp[lane]); hy[q] = bf2f(hp[64 + lane]);
        }
        #pragma unroll
        for (int q = 0; q < 8; ++q) GSTEP(Av[q], wwv[q], hx[q], hy[q])
    }
    for (; p < end; ++p) {
        int2 E = csr[p];
        float4 A = *(const float4*)(as + (size_t)E.x * 4);
        const ushort* q = h + (size_t)E.x * 128;
        float hx = bf2f(q[lane]), hy = bf2f(q[64 + lane]);
        float w = __int_as_float(E.y);
        GSTEP(A, w, hx, hy)
    }
    #undef GSTEP

    float o0 = acc0 / (den0 + 1e-16f);
    float o1 = acc1 / (den1 + 1e-16f);
    o0 = o0 > 0.f ? o0 : (__expf(o0) - 1.f);
    o1 = o1 > 0.f ? o1 : (__expf(o1) - 1.f);
    outp[(size_t)wid * 128 + lane]      = f2bf(o0);
    outp[(size_t)wid * 128 + 64 + lane] = f2bf(o1);
}

__global__ __launch_bounds__(256) void gat_node_64(
    const ushort* __restrict__ h, const float* __restrict__ as,
    const float* __restrict__ ad, const int* __restrict__ rowptr,
    const int2* __restrict__ csr, ushort* __restrict__ outp, int rows)
{
    int wid  = (blockIdx.x * 256 + threadIdx.x) >> 6;
    int lane = threadIdx.x & 63;
    if (wid >= rows) return;
    int start = rowptr[wid], end = rowptr[wid + 1];
    int hh = lane >> 4;                       // head: 0..3
    float adv = ad[wid * 4 + hh];
    float acc = 0.f, den = 0.f;

    #define GSTEP64(AA, ww, hv) { \
        float e = (hh & 2 ? (hh & 1 ? AA.w : AA.z) : (hh & 1 ? AA.y : AA.x)) + adv; \
        e = e > 0.f ? e : 0.2f * e; \
        float x = __expf(e) * ww; \
        den += x; acc += x * hv; }

    int p = start;
    if ((p & 1) && p < end) {
        int2 E = csr[p];
        float4 A = *(const float4*)(as + (size_t)E.x * 4);
        float hv = bf2f(h[(size_t)E.x * 64 + lane]);
        float w = __int_as_float(E.y);
        GSTEP64(A, w, hv)
        ++p;
    }
    for (; p + 8 <= end; p += 8) {
        int4 e0 = *(const int4*)(csr + p);
        int4 e1 = *(const int4*)(csr + p + 2);
        int4 e2 = *(const int4*)(csr + p + 4);
        int4 e3 = *(const int4*)(csr + p + 6);
        int ss[8] = { e0.x, e0.z, e1.x, e1.z, e2.x, e2.z, e3.x, e3.z };
        float wwv[8] = { __int_as_float(e0.y), __int_as_float(e0.w),
                         __int_as_float(e1.y), __int_as_float(e1.w),
                         __int_as_float(e2.y), __int_as_float(e2.w),
                         __int_as_float(e3.y), __int_as_float(e3.w) };
        float4 Av[8];
        #pragma unroll
        for (int q = 0; q < 8; ++q) Av[q] = *(const float4*)(as + (size_t)ss[q] * 4);
        float hv[8];
        #pragma unroll
        for (int q = 0; q < 8; ++q) hv[q] = bf2f(h[(size_t)ss[q] * 64 + lane]);
        #pragma unroll
        for (int q = 0; q < 8; ++q) GSTEP64(Av[q], wwv[q], hv[q])
    }
    for (; p < end; ++p) {
        int2 E = csr[p];
        float4 A = *(const float4*)(as + (size_t)E.x * 4);
        float hv = bf2f(h[(size_t)E.x * 64 + lane]);
        float w = __int_as_float(E.y);
        GSTEP64(A, w, hv)
    }
    #undef GSTEP64

    float o = acc / (den + 1e-16f);
    o = o > 0.f ? o : (__expf(o) - 1.f);
    outp[(size_t)wid * 64 + lane] = f2bf(o);
}

// ---------------------------------------------------------------------------
// Meso pooling via LDS histogram: 16 blocks per t; each block accumulates a
// [100][64] partial histogram with ds_add_f32 (no-return, pipelines freely),
// then flushes once with global atomics. Global atomics 5.12M -> 827K.
// ---------------------------------------------------------------------------
__global__ __launch_bounds__(256) void meso_lds(
    const ushort* __restrict__ g2, const int* __restrict__ part,
    const float* __restrict__ Dw, float* __restrict__ msum, float* __restrict__ mden)
{
    __shared__ float hist[NC_][64];
    __shared__ float hden[NC_];
    int t   = blockIdx.x >> 4;
    int blk = blockIdx.x & 15;
    int tid = threadIdx.x;
    for (int i = tid; i < NC_ * 64; i += 256) ((float*)hist)[i] = 0.f;
    for (int i = tid; i < NC_; i += 256) hden[i] = 0.f;
    __syncthreads();

    int wv = tid >> 6, lane = tid & 63;
    int wl = blk * 4 + wv;                    // wave index within t: 0..63
    for (int n = wl; n < N_; n += 64) {
        int gid = t * N_ + n;
        int pc = part[gid];
        float dv = Dw[gid];
        float val = dv * bf2f(g2[(size_t)gid * 64 + lane]);
        atomicAdd(&hist[pc][lane], val);
        if (lane == 0) atomicAdd(&hden[pc], dv);
    }
    __syncthreads();

    for (int i = tid; i < NC_ * 64; i += 256)
        atomicAdd(&msum[(size_t)t * NC_ * 64 + i], ((float*)hist)[i]);
    for (int i = tid; i < NC_; i += 256)
        atomicAdd(&mden[t * NC_ + i], hden[i]);
}

__global__ void agg_assemble(
    const ushort* __restrict__ g2, const int* __restrict__ part,
    const float* __restrict__ msum, const float* __restrict__ mden,
    ushort* __restrict__ agg)
{
    int idx = blockIdx.x * 256 + threadIdx.x;   // < TN*128
    int row = idx >> 7, d = idx & 127;
    ushort v;
    if (d < 64) {
        v = g2[(size_t)row * 64 + d];
    } else {
        int t = row / N_;
        int p = part[row];
        v = f2bf(msum[((size_t)(t * NC_ + p) << 6) + (d - 64)] / (mden[t * NC_ + p] + 1e-16f));
    }
    agg[idx] = v;
}

// ---------------------------------------------------------------------------
// Fused LSTM step: z = h@Wh + zx (zx = x@Wx + b, precomputed); gates from LDS;
// c,h updated in place. Block = 512 thr (8 waves), 32 rows x 512 cols.
// ---------------------------------------------------------------------------
__global__ __launch_bounds__(512) void lstm_fused(
    const ushort* __restrict__ hin, const ushort* __restrict__ WhT,
    const float* __restrict__ zx, float* __restrict__ c,
    ushort* __restrict__ hout)
{
    __shared__ float zt[32][516];
    int w = threadIdx.x >> 6, lane = threadIdx.x & 63;
    int quad = lane >> 4, l16 = lane & 15;
    int m0 = blockIdx.x * 32;
    int n0 = w * 64;

    f32x4 zf = {0.f, 0.f, 0.f, 0.f};
    f32x4 acc[2][4];
    #pragma unroll
    for (int rt = 0; rt < 2; ++rt)
        #pragma unroll
        for (int ct = 0; ct < 4; ++ct) acc[rt][ct] = zf;

    #pragma unroll
    for (int k0 = 0; k0 < 128; k0 += 32) {
        int kk = k0 + quad * 8;
        bf16x8 a0 = *(const bf16x8*)(hin + (size_t)(m0 + l16) * 128 + kk);
        bf16x8 a1 = *(const bf16x8*)(hin + (size_t)(m0 + 16 + l16) * 128 + kk);
        bf16x8 b[4];
        #pragma unroll
        for (int ct = 0; ct < 4; ++ct)
            b[ct] = *(const bf16x8*)(WhT + (size_t)(n0 + ct * 16 + l16) * 128 + kk);
        #pragma unroll
        for (int ct = 0; ct < 4; ++ct) {
            acc[0][ct] = __builtin_amdgcn_mfma_f32_16x16x32_bf16(a0, b[ct], acc[0][ct], 0, 0, 0);
            acc[1][ct] = __builtin_amdgcn_mfma_f32_16x16x32_bf16(a1, b[ct], acc[1][ct], 0, 0, 0);
        }
    }

    #pragma unroll
    for (int rt = 0; rt < 2; ++rt) {
        #pragma unroll
        for (int r = 0; r < 4; ++r) {
            int li = rt * 16 + quad * 4 + r;
            size_t gi = (size_t)(m0 + li);
            #pragma unroll
            for (int ct = 0; ct < 4; ++ct) {
                int j = n0 + ct * 16 + l16;
                zt[li][j] = acc[rt][ct][r] + zx[gi * 512 + j];
            }
        }
    }
    __syncthreads();

    int r  = threadIdx.x >> 4;
    int j0 = (threadIdx.x & 15) * 8;
    int gi = m0 + r;
    if (gi < N_) {
        f32x4 vi[2], vf[2], vg[2], vo[2], vc[2];
        #pragma unroll
        for (int hb = 0; hb < 2; ++hb) {
            int jj = j0 + hb * 4;
            vi[hb] = *(const f32x4*)&zt[r][jj];
            vf[hb] = *(const f32x4*)&zt[r][128 + jj];
            vg[hb] = *(const f32x4*)&zt[r][256 + jj];
            vo[hb] = *(const f32x4*)&zt[r][384 + jj];
            vc[hb] = *(const f32x4*)(c + (size_t)gi * 128 + jj);
        }
        u16x8 ho;
        #pragma unroll
        for (int e = 0; e < 8; ++e) {
            int hb = e >> 2, q = e & 3;
            float si = fast_sigmoid(vi[hb][q]);
            float sf = fast_sigmoid(vf[hb][q]);
            float so = fast_sigmoid(vo[hb][q]);
            float cn = sf * vc[hb][q] + si * fast_tanh(vg[hb][q]);
            vc[hb][q] = cn;
            ho[e] = f2bf(so * fast_tanh(cn));
        }
        *(f32x4*)(c + (size_t)gi * 128 + j0)     = vc[0];
        *(f32x4*)(c + (size_t)gi * 128 + j0 + 4) = vc[1];
        *(u16x8*)(hout + (size_t)gi * 128 + j0)  = ho;
    }
}

// ---------------------------------------------------------------------------
// Column sum-of-squares for emb (fp32), then normalize -> bf16 + per-row sq
// ---------------------------------------------------------------------------
__global__ __launch_bounds__(256) void col_sumsq(const float* __restrict__ emb,
                                                 float* __restrict__ colss)
{
    int tid = threadIdx.x;
    int col = tid & 63, rq = tid >> 6;
    float s = 0.f;
    for (int r = blockIdx.x * 4 + rq; r < N_; r += 40 * 4) {
        float v = emb[(size_t)r * 64 + col];
        s += v * v;
    }
    __shared__ float red[256];
    red[tid] = s;
    __syncthreads();
    if (tid < 64)
        atomicAdd(&colss[tid], red[tid] + red[tid + 64] + red[tid + 128] + red[tid + 192]);
}

// sq computed from the bf16-ROUNDED values so the i==j cancellation in the
// final dist is exact.
__global__ __launch_bounds__(256) void norm_rows(const float* __restrict__ emb,
                                                 const float* __restrict__ colss,
                                                 ushort* __restrict__ embb,
                                                 float* __restrict__ sq, int rows)
{
    int wid  = (blockIdx.x * 256 + threadIdx.x) >> 6;
    int lane = threadIdx.x & 63;
    if (wid >= rows) return;
    float nv = emb[(size_t)wid * 64 + lane] / sqrtf(colss[lane]);
    ushort ub = f2bf(nv);
    embb[(size_t)wid * 64 + lane] = ub;
    float nq = bf2f(ub);
    float q = nq * nq;
    #pragma unroll
    for (int m = 1; m <= 32; m <<= 1) q += __shfl_xor(q, m);
    if (lane == 0) sq[wid] = q;
}

// ---------------------------------------------------------------------------
// Fused final, MFMA: S = scal.scal^T, G = emb.emb^T (K=64, bf16),
// out = 1 + tanh((2G - sq_i - sq_j) * S).
// Full-line NT store scheme: 128-row band x 640 cols per block; per 128-col
// tile, epilogue -> LDS -> copy-out with odd rows shifted -64 B so every
// dwordx4x32-lane store covers exactly 4 full 128 B lines (row stride
// 40000 B = 64 mod 128). Edge strip double-buffered in LDS.
// ---------------------------------------------------------------------------
#define FTJ_   5
#define FCOLS_ (FTJ_*128)

__global__ __launch_bounds__(256) void final_adj_mfma(
    const ushort* __restrict__ embb, const ushort* __restrict__ scalb,
    const float* __restrict__ sq, float* __restrict__ outp)
{
    __shared__ float cur[128][132];      // 128x128 tile, +4 pad: conflict-free b128
    __shared__ float edg[2][64][16];     // odd local rows' cols [112,128) of tile t

    int w = threadIdx.x >> 6, lane = threadIdx.x & 63;
    int quad = lane >> 4, l16 = lane & 15;
    int bi = blockIdx.y * 128;
    int Wb = blockIdx.x * FCOLS_;
    int wi = bi + (w >> 1) * 64;         // wave row base (global)

    float sqi[4];
    #pragma unroll
    for (int rt = 0; rt < 4; ++rt) sqi[rt] = sq[wi + rt * 16 + l16];

    int tLast = (N_ - 1 - Wb) / 128;
    if (tLast > FTJ_ - 1) tLast = FTJ_ - 1;

    for (int t = 0; t <= tLast; ++t) {
        int Wt = Wb + t * 128;
        int wj = Wt + (w & 1) * 64;      // wave col base (global)

        f32x4 zf = {0.f, 0.f, 0.f, 0.f};
        f32x4 accG[4][4], accS[4][4];
        #pragma unroll
        for (int rt = 0; rt < 4; ++rt)
            #pragma unroll
            for (int ct = 0; ct < 4; ++ct) { accG[rt][ct] = zf; accS[rt][ct] = zf; }

        #pragma unroll
        for (int ks = 0; ks < 2; ++ks) {
            int k0 = ks * 32 + quad * 8;
            bf16x8 ae[4], af[4], be[4], bs[4];
            #pragma unroll
            for (int q = 0; q < 4; ++q) {
                int ri = wi + q * 16 + l16;
                int rj = wj + q * 16 + l16;          // max 10111 < NPAD_
                ae[q] = *(const bf16x8*)(embb  + (size_t)ri * 64 + k0);
                af[q] = *(const bf16x8*)(scalb + (size_t)ri * 64 + k0);
                be[q] = *(const bf16x8*)(embb  + (size_t)rj * 64 + k0);
                bs[q] = *(const bf16x8*)(scalb + (size_t)rj * 64 + k0);
            }
            // Swapped operands (G,S symmetric): i = wave_row + rt*16 + l16,
            // j = wave_col + ct*16 + quad*4 + r  (bitwise-identical values).
            #pragma unroll
            for (int rt = 0; rt < 4; ++rt)
                #pragma unroll
                for (int ct = 0; ct < 4; ++ct) {
                    accG[rt][ct] = __builtin_amdgcn_mfma_f32_16x16x32_bf16(be[ct], ae[rt], accG[rt][ct], 0, 0, 0);
                    accS[rt][ct] = __builtin_amdgcn_mfma_f32_16x16x32_bf16(bs[ct], af[rt], accS[rt][ct], 0, 0, 0);
                }
        }

        __syncthreads();   // previous copy-out finished reading cur/edg

        #pragma unroll
        for (int rt = 0; rt < 4; ++rt) {
            int li = (w >> 1) * 64 + rt * 16 + l16;
            float si = sqi[rt];
            #pragma unroll
            for (int ct = 0; ct < 4; ++ct) {
                int lj = (w & 1) * 64 + ct * 16 + quad * 4;
                const float4 sj = *(const float4*)(sq + Wt + lj);
                float sjr[4] = { sj.x, sj.y, sj.z, sj.w };
                f32x4 v;
                #pragma unroll
                for (int r = 0; r < 4; ++r) {
                    float G = accG[rt][ct][r], S = accS[rt][ct][r];
                    float dist = 2.f * G - si - sjr[r];
                    float e = __expf(2.f * dist * S);
                    v[r] = 2.f - 2.f / (e + 1.f);
                }
                *(f32x4*)&cur[li][lj] = v;
                if ((w & 1) && ct == 3 && (li & 1))
                    *(f32x4*)&edg[t & 1][li >> 1][quad * 4] = v;
            }
        }

        __syncthreads();

        int lane5 = lane & 31;
        #pragma unroll
        for (int pass = 0; pass < 16; ++pass) {
            int r = pass * 8 + (lane >> 5) * 4 + w;
            int i = bi + r;
            if (i < N_) {
                if (!(r & 1)) {
                    int gcol = Wt + lane5 * 4;
                    if (gcol < N_)
                        __builtin_nontemporal_store(*(const f32x4*)&cur[r][lane5 * 4],
                            (f32x4*)(outp + (size_t)i * N_ + gcol));
                } else {
                    int gcol = Wt - 16 + lane5 * 4;
                    if ((t > 0 || lane5 >= 4) && gcol >= 0 && gcol < N_) {
                        f32x4 v;
                        if (lane5 < 4) v = *(const f32x4*)&edg[(t & 1) ^ 1][r >> 1][lane5 * 4];
                        else           v = *(const f32x4*)&cur[r][lane5 * 4 - 16];
                        __builtin_nontemporal_store(v,
                            (f32x4*)(outp + (size_t)i * N_ + gcol));
                    }
                }
            }
        }
    }

    // flush: trailing 16 cols of the band's last tile, odd rows (cur intact)
    {
        int tid = threadIdx.x;
        int r = ((tid >> 2) << 1) | 1;            // odd rows 1..127
        int k = (tid & 3) * 4;
        int i = bi + r;
        int gcol = Wb + tLast * 128 + 112 + k;
        if (i < N_ && gcol < N_) {
            f32x4 v = *(const f32x4*)&cur[r][112 + k];
            __builtin_nontemporal_store(v, (f32x4*)(outp + (size_t)i * N_ + gcol));
        }
    }
}

// ---------------------------------------------------------------------------
extern "C" void kernel_launch(void* const* d_in, const int* in_sizes, int n_in,
                              void* d_out, int out_size, void* d_ws, size_t ws_size,
                              hipStream_t stream)
{
    (void)in_sizes; (void)n_in; (void)out_size; (void)ws_size;
    const float* feat    = (const float*)d_in[0];
    const float* eweight = (const float*)d_in[1];
    const float* Dw      = (const float*)d_in[2];
    const float* W1      = (const float*)d_in[3];
    const float* a_src1  = (const float*)d_in[4];
    const float* a_dst1  = (const float*)d_in[5];
    const float* W2      = (const float*)d_in[6];
    const float* a_src2  = (const float*)d_in[7];
    const float* a_dst2  = (const float*)d_in[8];
    const float* Wx      = (const float*)d_in[9];
    const float* Wh      = (const float*)d_in[10];
    const float* b_lstm  = (const float*)d_in[11];
    const float* emb_W   = (const float*)d_in[12];
    const float* emb_b   = (const float*)d_in[13];
    const float* scal_W  = (const float*)d_in[14];
    const float* scal_b  = (const float*)d_in[15];
    const int*   eidx    = (const int*)d_in[16];
    const int*   part    = (const int*)d_in[17];

    // ---- scratch layout (floats) inside d_out (dead before final_adj) ----
    float* out = (float*)d_out;
    ushort* h1b   = (ushort*)(out + 0);          // 80000x128 bf16 (5,120,000 f)
    ushort* g1b   = (ushort*)(out + 5120000);    // 80000x128 bf16
    ushort* h2b   = (ushort*)(out + 10240000);   // 80000x64 bf16
    ushort* g2b   = (ushort*)(out + 12800000);   // 80000x64 bf16
    float* as1    = out + 15360000;              // TN*4
    float* ad1    = out + 15680000;
    float* as2    = out + 16000000;
    float* ad2    = out + 16320000;
    int*   rowptr = (int*)(out + 16640000);      // TN+1
    int*   cursor = (int*)(out + 16720064);
    int*   counts = (int*)(out + 16800064);
    int2*  csr_sw = (int2*)(out + 16880064);     // TE int2 (5.12M ints)
    float* msum   = out + 22000064;              // T*100*64
    float* mden   = out + 22051264;              // T*100
    ushort* aggb  = (ushort*)(out + 22052064);   // 80000x128 bf16
    float* ZX     = out + 27172064;              // 80000x512 fp32
    float* cstate = out + 73252064;              // 10000x128 fp32
    ushort* hbf   = (ushort*)(out + 74532064);   // NPAD x128 bf16 (647,168 f)
    ushort* featb = (ushort*)(out + 75179232);   // 80000x128 bf16
    ushort* W1T   = (ushort*)(out + 80299232);   // 128x128
    ushort* W2T   = (ushort*)(out + 80307424);   // 64x128
    ushort* WxT   = (ushort*)(out + 80311520);   // 512x128
    ushort* WhT   = (ushort*)(out + 80344288);   // 512x128
    ushort* eWT   = (ushort*)(out + 80377056);   // 64x128
    ushort* sWT   = (ushort*)(out + 80381152);   // 64x128
    float* embf   = out + 80385248;              // 10000x64 fp32
    float* colss  = out + 81025248;              // 64

    // ---- live-at-final buffers in d_ws ----
    ushort* embb  = (ushort*)d_ws;               // NPAD x 64 bf16
    ushort* scalb = embb + (size_t)NPAD_ * 64;   // NPAD x 64 bf16
    float*  sq    = (float*)(scalb + (size_t)NPAD_ * 64);  // NPAD fp32

    // ---- zero-init accumulation targets ----
    hipMemsetAsync(counts, 0, TN_ * sizeof(int), stream);
    hipMemsetAsync(msum, 0, (T_ * NC_ * 64 + T_ * NC_) * sizeof(float), stream);
    hipMemsetAsync(cstate, 0, (size_t)N_ * DR_ * sizeof(float), stream);
    hipMemsetAsync(hbf, 0, (size_t)NPAD_ * DR_ * sizeof(ushort), stream);  // h0 = 0 (+pad)
    hipMemsetAsync(colss, 0, 64 * sizeof(float), stream);

    // ---- converts ----
    conv_feat<<<5000, 256, 0, stream>>>(feat, featb, TN_ * F_ / 8);
    conv_weights<<<672, 256, 0, stream>>>(W1, W2, Wx, Wh, emb_W, scal_W,
                                          W1T, W2T, WxT, WhT, eWT, sWT);

    // ---- GAT layer 1 (batched over T) ----
    gemm_bf16<<<dim3(2, 625), 256, 0, stream>>>(featb, W1T, nullptr, h1b, nullptr, nullptr, TN_, 128, 128, 0);
    att_vec128<<<TN_/4, 256, 0, stream>>>(h1b, a_src1, a_dst1, as1, ad1, TN_);
    count_edges<<<(TE_+255)/256, 256, 0, stream>>>(eidx, counts);
    scan_per_t<<<T_, 1024, 0, stream>>>(counts, rowptr, cursor);
    fill_csr<<<(TE_+255)/256, 256, 0, stream>>>(eidx, eweight, cursor, csr_sw);
    gat_node_128<<<TN_/4, 256, 0, stream>>>(h1b, as1, ad1, rowptr, csr_sw, g1b, TN_);

    // ---- GAT layer 2 ----
    gemm_bf16<<<dim3(1, 625), 256, 0, stream>>>(g1b, W2T, nullptr, h2b, nullptr, nullptr, TN_, 128, 64, 0);
    att_vec64<<<TN_/4, 256, 0, stream>>>(h2b, a_src2, a_dst2, as2, ad2, TN_);
    gat_node_64<<<TN_/4, 256, 0, stream>>>(h2b, as2, ad2, rowptr, csr_sw, g2b, TN_);

    // ---- meso + agg ----
    meso_lds<<<T_ * 16, 256, 0, stream>>>(g2b, part, Dw, msum, mden);
    agg_assemble<<<TN_*128/256, 256, 0, stream>>>(g2b, part, msum, mden, aggb);

    // ---- LSTM: batched input projection, then 8 fused recurrent steps ----
    gemm_bf16<<<dim3(8, 625), 256, 0, stream>>>(aggb, WxT, ZX, nullptr, b_lstm, nullptr, TN_, 128, 512, 0);
    for (int t = 0; t < T_; ++t)
        lstm_fused<<<(N_ + 31) / 32, 512, 0, stream>>>(hbf, WhT, ZX + (size_t)t * N_ * 512,
                                                       cstate, hbf);

    // ---- decoder heads ----
    gemm_bf16<<<dim3(1, 79), 256, 0, stream>>>(hbf, eWT, embf, nullptr, emb_b, nullptr, N_, 128, 64, 1);
    gemm_bf16<<<dim3(1, 79), 256, 0, stream>>>(hbf, sWT, nullptr, scalb, scal_b, nullptr, N_, 128, 64, 2);
    col_sumsq<<<40, 256, 0, stream>>>(embf, colss);
    norm_rows<<<(N_+3)/4, 256, 0, stream>>>(embf, colss, embb, sq, N_);

    // ---- fused final ----
    final_adj_mfma<<<dim3(16, 79), 256, 0, stream>>>(embb, scalb, sq, out);
}